// Round 1
// 846.411 us; speedup vs baseline: 1.0000x; 1.0000x over previous
//
#include <hip/hip_runtime.h>
#include <math.h>

typedef _Float16 f16;
typedef f16 f16x2 __attribute__((ext_vector_type(2)));
typedef f16 f16x8 __attribute__((ext_vector_type(8)));
typedef float f32x4 __attribute__((ext_vector_type(4)));

template <int V> struct VecT;
template <> struct VecT<2> { using T = f16 __attribute__((ext_vector_type(2))); };
template <> struct VecT<8> { using T = f16 __attribute__((ext_vector_type(8))); };

__device__ __forceinline__ unsigned ordf(float f) {
  unsigned u = __float_as_uint(f);
  return (u >> 31) ? ~u : (u | 0x80000000u);
}
__device__ __forceinline__ float unordf(unsigned u) {
  return (u >> 31) ? __uint_as_float(u & 0x7fffffffu) : __uint_as_float(~u);
}

// ---------------------------------------------------------------------------
// CSR build: histogram of dst -> 3-stage parallel scan -> fill permutation
// Edge id space: [0, E) = real edges, [E, E+N) = self loops (src=dst=id-E)
// ---------------------------------------------------------------------------

__global__ void k_count(const int* __restrict__ dstArr, int* __restrict__ cnt,
                        int E, int Et) {
  int i = blockIdx.x * blockDim.x + threadIdx.x;
  if (i >= Et) return;
  int d = (i < E) ? dstArr[i] : (i - E);
  atomicAdd(&cnt[d], 1);
}

__global__ __launch_bounds__(256) void k_scanA(const int* __restrict__ cnt,
                                               int* __restrict__ row_ptr,
                                               int* __restrict__ bsum, int n) {
  __shared__ int part[256];
  int t = threadIdx.x;
  int base = blockIdx.x * 1024 + t * 4;
  int4 v = make_int4(0, 0, 0, 0);
  if (base + 3 < n) v = *(const int4*)&cnt[base];
  else {
    if (base + 0 < n) v.x = cnt[base + 0];
    if (base + 1 < n) v.y = cnt[base + 1];
    if (base + 2 < n) v.z = cnt[base + 2];
    if (base + 3 < n) v.w = cnt[base + 3];
  }
  int s = v.x + v.y + v.z + v.w;
  part[t] = s;
  __syncthreads();
  for (int off = 1; off < 256; off <<= 1) {
    int x = (t >= off) ? part[t - off] : 0;
    __syncthreads();
    part[t] += x;
    __syncthreads();
  }
  int p0 = (t == 0) ? 0 : part[t - 1];
  int p1 = p0 + v.x, p2 = p1 + v.y, p3 = p2 + v.z;
  if (base + 0 < n) row_ptr[base + 0] = p0;
  if (base + 1 < n) row_ptr[base + 1] = p1;
  if (base + 2 < n) row_ptr[base + 2] = p2;
  if (base + 3 < n) row_ptr[base + 3] = p3;
  if (t == 255) bsum[blockIdx.x] = part[255];
}

__global__ __launch_bounds__(1024) void k_scanB(int* __restrict__ bsum, int nb) {
  __shared__ int part[1024];
  int t = threadIdx.x;
  int v = (t < nb) ? bsum[t] : 0;
  part[t] = v;
  __syncthreads();
  for (int off = 1; off < 1024; off <<= 1) {
    int x = (t >= off) ? part[t - off] : 0;
    __syncthreads();
    part[t] += x;
    __syncthreads();
  }
  if (t < nb) bsum[t] = (t == 0) ? 0 : part[t - 1];
  if (t == 1023) bsum[nb] = part[1023];
}

__global__ void k_scanC(int* __restrict__ row_ptr, int* __restrict__ cursor,
                        const int* __restrict__ bsum, int n, int nb) {
  int i = blockIdx.x * blockDim.x + threadIdx.x;
  if (i < n) {
    int v = row_ptr[i] + bsum[i >> 10];
    row_ptr[i] = v;
    cursor[i] = v;
  }
  if (i == n) row_ptr[n] = bsum[nb];
}

__global__ void k_fill(const int* __restrict__ dstArr, int* __restrict__ cursor,
                       int* __restrict__ perm, int E, int Et) {
  int i = blockIdx.x * blockDim.x + threadIdx.x;
  if (i >= Et) return;
  int d = (i < E) ? dstArr[i] : (i - E);
  int pos = atomicAdd(&cursor[d], 1);
  perm[pos] = i;
}

// ---------------------------------------------------------------------------
// fp32 -> fp16 conversion, 4 segments in one launch (each n multiple of 4)
// ---------------------------------------------------------------------------
__global__ void k_f2h4(const float* s0, f16* d0, int n0,
                       const float* s1, f16* d1, int n1,
                       const float* s2, f16* d2, int n2,
                       const float* s3, f16* d3, int n3) {
  int i = blockIdx.x * blockDim.x + threadIdx.x;
  const float* s; f16* d;
  if (i < n0) { s = s0; d = d0; }
  else if ((i -= n0) < n1) { s = s1; d = d1; }
  else if ((i -= n1) < n2) { s = s2; d = d2; }
  else if ((i -= n2) < n3) { s = s3; d = d3; }
  else return;
  float4 v = ((const float4*)s)[i];
  union { f16 h[4]; double dd; } u;
  u.h[0] = (f16)v.x; u.h[1] = (f16)v.y; u.h[2] = (f16)v.z; u.h[3] = (f16)v.w;
  ((double*)d)[i] = u.dd;
}

// ---------------------------------------------------------------------------
// HGEMM (fp16 MFMA, fp32 accumulate): C[M,Nn] = A[M,K] @ B[Nn,K]^T
// 128x128 tile, BK=32, 256 thr = 4 waves, wave = 64x64 quadrant (4x4 MFMAs).
// Staging via global_load_lds width=16 (async direct-to-LDS). LDS layout:
// natural stride 32 f16 (64 B/row) with xor chunk swizzle
//   chunk_lds = chunk_glob ^ ((row>>1)&3)
// -> write side matches the wave-uniform-base+lane*16 landing pattern,
//    read side spreads 64 b128 lanes over all 8 bank groups (2-way, free).
// Fused GAT-attention epilogue (block covers one head's 128 cols).
// ---------------------------------------------------------------------------
__global__ __launch_bounds__(256) void k_hgemm_nt(
    const f16* __restrict__ A, const f16* __restrict__ B,
    f16* __restrict__ C, int M, int Nn, int K,
    const float* __restrict__ a_src, const float* __restrict__ a_dst,
    float* __restrict__ sArr, float* __restrict__ dArr,
    unsigned* __restrict__ gmaxU, int H) {
  __shared__ f16 As[128 * 32];
  __shared__ f16 Bs[128 * 32];
  int tid = threadIdx.x;
  int wave = tid >> 6, lane = tid & 63;
  int quad = lane >> 4, l16 = lane & 15;
  int m0 = blockIdx.y * 128, n0 = blockIdx.x * 128;
  int wm = (wave & 1) * 64, wn = (wave >> 1) * 64;

  // ---- staging addresses (wave w stages rows w*16.. and 64+w*16.. of A and B)
  int lr = lane >> 2;            // row within 16-row group
  int lc = lane & 3;             // lds chunk slot this lane fills
  int chunk = lc ^ ((lr >> 1) & 3);  // global chunk to fetch (swizzle)
  int rb0 = wave * 16;
  int rb1 = 64 + wave * 16;
  int ga0 = m0 + rb0 + lr; if (ga0 >= M) ga0 = M - 1;
  int ga1 = m0 + rb1 + lr; if (ga1 >= M) ga1 = M - 1;
  const f16* gA0 = A + (size_t)ga0 * K + chunk * 8;
  const f16* gA1 = A + (size_t)ga1 * K + chunk * 8;
  const f16* gB0 = B + (size_t)(n0 + rb0 + lr) * K + chunk * 8;
  const f16* gB1 = B + (size_t)(n0 + rb1 + lr) * K + chunk * 8;
  f16* lA0 = &As[rb0 * 32];
  f16* lA1 = &As[rb1 * 32];
  f16* lB0 = &Bs[rb0 * 32];
  f16* lB1 = &Bs[rb1 * 32];

  // ---- fragment read pointers (chunk = quad ^ ((l16>>1)&3))
  int rsw = (quad ^ ((l16 >> 1) & 3)) * 8;
  const f16* Ard[4];
  const f16* Brd[4];
#pragma unroll
  for (int i = 0; i < 4; ++i) {
    Ard[i] = &As[(wm + i * 16 + l16) * 32 + rsw];
    Brd[i] = &Bs[(wn + i * 16 + l16) * 32 + rsw];
  }

  f32x4 acc[4][4];
#pragma unroll
  for (int i = 0; i < 4; ++i)
#pragma unroll
    for (int j = 0; j < 4; ++j) acc[i][j] = (f32x4)(0.f);

  for (int k0 = 0; k0 < K; k0 += 32) {
    __syncthreads();  // previous iteration's LDS reads complete
    __builtin_amdgcn_global_load_lds(
        (const __attribute__((address_space(1))) void*)(gA0 + k0),
        (__attribute__((address_space(3))) void*)lA0, 16, 0, 0);
    __builtin_amdgcn_global_load_lds(
        (const __attribute__((address_space(1))) void*)(gA1 + k0),
        (__attribute__((address_space(3))) void*)lA1, 16, 0, 0);
    __builtin_amdgcn_global_load_lds(
        (const __attribute__((address_space(1))) void*)(gB0 + k0),
        (__attribute__((address_space(3))) void*)lB0, 16, 0, 0);
    __builtin_amdgcn_global_load_lds(
        (const __attribute__((address_space(1))) void*)(gB1 + k0),
        (__attribute__((address_space(3))) void*)lB1, 16, 0, 0);
    __syncthreads();  // drains vmcnt -> staged tile visible to all waves
    f16x8 af[4], bf[4];
#pragma unroll
    for (int i = 0; i < 4; ++i) af[i] = *(const f16x8*)Ard[i];
#pragma unroll
    for (int j = 0; j < 4; ++j) bf[j] = *(const f16x8*)Brd[j];
#pragma unroll
    for (int i = 0; i < 4; ++i)
#pragma unroll
      for (int j = 0; j < 4; ++j)
        acc[i][j] = __builtin_amdgcn_mfma_f32_16x16x32_f16(af[i], bf[j], acc[i][j], 0, 0, 0);
  }

  // ---- C store ----
#pragma unroll
  for (int i = 0; i < 4; ++i) {
#pragma unroll
    for (int r = 0; r < 4; ++r) {
      int m = m0 + wm + i * 16 + quad * 4 + r;
      if (m < M) {
        f16* Cp = C + (size_t)m * Nn + n0 + wn + l16;
#pragma unroll
        for (int j = 0; j < 4; ++j) Cp[j * 16] = (f16)acc[i][j][r];
      }
    }
  }

  // ---- fused attention scalars ----
  float av[4], ad[4];
#pragma unroll
  for (int j = 0; j < 4; ++j) {
    int col = n0 + wn + l16 + j * 16;
    av[j] = a_src[col];
    ad[j] = a_dst[col];
  }
  float sp[16], dp[16];
#pragma unroll
  for (int i = 0; i < 4; ++i)
#pragma unroll
    for (int r = 0; r < 4; ++r) {
      float ss = 0.f, dd = 0.f;
#pragma unroll
      for (int j = 0; j < 4; ++j) {
        ss += acc[i][j][r] * av[j];
        dd += acc[i][j][r] * ad[j];
      }
#pragma unroll
      for (int msk = 1; msk < 16; msk <<= 1) {
        ss += __shfl_xor(ss, msk);
        dd += __shfl_xor(dd, msk);
      }
      sp[i * 4 + r] = ss;
      dp[i * 4 + r] = dd;
    }

  __syncthreads();  // done reading As/Bs; reuse as float scratch
  float* fb = (float*)As;
  int wv = wn >> 6;
  if (l16 == 0) {
#pragma unroll
    for (int i = 0; i < 4; ++i)
#pragma unroll
      for (int r = 0; r < 4; ++r) {
        int row = wm + i * 16 + quad * 4 + r;
        fb[wv * 128 + row] = sp[i * 4 + r];
        fb[256 + wv * 128 + row] = dp[i * 4 + r];
      }
  }
  __syncthreads();
  if (tid < 128) {
    int m = m0 + tid;
    if (m < M) {
      float s = fb[tid] + fb[128 + tid];
      float d = fb[256 + tid] + fb[384 + tid];
      int head = n0 >> 7;
      sArr[(size_t)m * H + head] = s;
      dArr[(size_t)m * H + head] = d;
      atomicMax(&gmaxU[head], ordf(s));
    }
  }
}

// ---------------------------------------------------------------------------
// Segment softmax + aggregation: ONE WAVE PER NODE, no barriers.
// v2: per-chunk (soff, w) pairs staged in LDS interleaved per head so the
// inner loop is ONE ds_read_b64 per edge (replaces 5 bpermutes + selects),
// denominator hoisted to a per-chunk lane accumulator + one final wave
// reduction, and the feature gathers are software-pipelined in groups of 4
// with double-buffered registers (8 gathers in flight per wave). Tail edges
// padded with w=0/soff=0 (hits node 0's L1-hot row) so the unrolled body is
// branch-free and statically indexed.
// Shift = leaky(gmax + d_n) >= segment max (leaky monotone; softmax
// shift-invariant). gmax passed as order-preserving uint.
// ---------------------------------------------------------------------------
template <int HH, int CT, bool DOELU, typename OutT>
__global__ __launch_bounds__(256) void k_aggregate(
    const f16* __restrict__ hin, const float* __restrict__ sArr,
    const float* __restrict__ dArr, const int* __restrict__ row_ptr,
    const int* __restrict__ perm, const int* __restrict__ srcArr,
    const unsigned* __restrict__ gmaxU, const float* __restrict__ bias,
    OutT* __restrict__ outp, int N, int E) {
  constexpr int VEC = CT / 64;
  constexpr int CPER = CT / HH;
  using gvec = typename VecT<VEC>::T;

  __shared__ int2 pairs[4][64 * HH];  // [wave][edge*HH + h] = {soff, w_h}

  int wave = threadIdx.x >> 6;
  int lane = threadIdx.x & 63;
  int n = blockIdx.x * 4 + wave;
  if (n >= N) return;
  int e0 = row_ptr[n];
  int deg = row_ptr[n + 1] - e0;

  const int myhead = (HH == 1) ? 0 : (lane * VEC) / CPER;
  const int laneByte = lane * VEC * 2;

  float dloc[HH], mn[HH];
#pragma unroll
  for (int h = 0; h < HH; ++h) {
    dloc[h] = dArr[n * HH + h];
    float m = unordf(gmaxU[h]) + dloc[h];
    mn[h] = (m > 0.f) ? m : 0.2f * m;
  }

  float acc[VEC];
#pragma unroll
  for (int k = 0; k < VEC; ++k) acc[k] = 0.f;
  float dsum[HH];
#pragma unroll
  for (int h = 0; h < HH; ++h) dsum[h] = 0.f;

  int2* pw = &pairs[wave][0];

#define LOADG(VB, WB, g)                                                      \
  do {                                                                        \
    _Pragma("unroll") for (int j_ = 0; j_ < 4; ++j_) {                        \
      int2 p_ = pw[((g) * 4 + j_) * HH + myhead];                             \
      WB[j_] = __int_as_float(p_.y);                                          \
      VB[j_] = *(const gvec*)((const char*)hin + (unsigned)(p_.x + laneByte));\
    }                                                                         \
  } while (0)

#define FMAG(VB, WB)                                                          \
  do {                                                                        \
    _Pragma("unroll") for (int j_ = 0; j_ < 4; ++j_)                          \
        _Pragma("unroll") for (int k_ = 0; k_ < VEC; ++k_)                    \
            acc[k_] += WB[j_] * (float)VB[j_][k_];                            \
  } while (0)

  for (int base = 0; base < deg; base += 64) {
    int cn = min(64, deg - base);

    // ---- producer phase: this lane's edge -> (soff, w[h]) ----
    int soff = 0;
    float w_l[HH];
#pragma unroll
    for (int h = 0; h < HH; ++h) w_l[h] = 0.f;
    if (lane < cn) {
      int eid = perm[e0 + base + lane];
      int s = (eid < E) ? srcArr[eid] : (eid - E);
      soff = s * (CT * 2);
      if (HH == 4) {
        float4 sv = ((const float4*)sArr)[s];
        float svv[4] = {sv.x, sv.y, sv.z, sv.w};
#pragma unroll
        for (int h = 0; h < 4; ++h) {
          float e = svv[h] + dloc[h];
          e = (e > 0.f) ? e : 0.2f * e;
          w_l[h] = __expf(e - mn[h]);
        }
      } else {
        float e = sArr[s] + dloc[0];
        e = (e > 0.f) ? e : 0.2f * e;
        w_l[0] = __expf(e - mn[0]);
      }
    }
#pragma unroll
    for (int h = 0; h < HH; ++h) dsum[h] += w_l[h];

    if (HH == 4) {
      int4 p0 = make_int4(soff, __float_as_int(w_l[0]), soff, __float_as_int(w_l[1]));
      int4 p1 = make_int4(soff, __float_as_int(w_l[2]), soff, __float_as_int(w_l[3]));
      *(int4*)&pw[lane * 4] = p0;
      *(int4*)&pw[lane * 4 + 2] = p1;
    } else {
      pw[lane] = make_int2(soff, __float_as_int(w_l[0]));
    }
    // same-wave LDS visibility: drain DS queue; "memory" clobber orders the
    // surrounding ds_write/ds_read (no cross-wave sharing -> no s_barrier)
    asm volatile("s_waitcnt lgkmcnt(0)" ::: "memory");

    // ---- consumer phase: pipelined gather+FMA, groups of 4 edges ----
    int cng = (cn + 3) >> 2;  // tail edges padded with w=0 by producer
    gvec vA[4], vB[4];
    float wA[4], wB[4];
    LOADG(vA, wA, 0);
    int g = 0;
    while (g + 2 < cng) {
      LOADG(vB, wB, g + 1);
      FMAG(vA, wA);
      LOADG(vA, wA, g + 2);
      FMAG(vB, wB);
      g += 2;
    }
    if (g + 1 < cng) {
      LOADG(vB, wB, g + 1);
      FMAG(vA, wA);
      FMAG(vB, wB);
    } else {
      FMAG(vA, wA);
    }
  }
#undef LOADG
#undef FMAG

  // ---- denominator: one wave reduction per head, then per-lane select ----
  float dn;
  if (HH == 4) {
    float t0 = dsum[0], t1 = dsum[1], t2 = dsum[2], t3 = dsum[3];
#pragma unroll
    for (int m = 1; m < 64; m <<= 1) {
      t0 += __shfl_xor(t0, m);
      t1 += __shfl_xor(t1, m);
      t2 += __shfl_xor(t2, m);
      t3 += __shfl_xor(t3, m);
    }
    dn = (myhead < 2) ? (myhead == 0 ? t0 : t1) : (myhead == 2 ? t2 : t3);
  } else {
    float t0 = dsum[0];
#pragma unroll
    for (int m = 1; m < 64; m <<= 1) t0 += __shfl_xor(t0, m);
    dn = t0;
  }
  dn += 1e-16f;

  struct alignas(sizeof(OutT) * VEC) OutV { OutT v[VEC]; } ov;
#pragma unroll
  for (int k = 0; k < VEC; ++k) {
    float v = acc[k] / dn + bias[lane * VEC + k];
    if (DOELU) v = (v > 0.f) ? v : expm1f(v);
    ov.v[k] = (OutT)v;
  }
  *(OutV*)(outp + (size_t)n * CT + lane * VEC) = ov;
}

// ---------------------------------------------------------------------------
// Allocation head (Wh1 staged in LDS, persistent blocks)
// ---------------------------------------------------------------------------
__global__ __launch_bounds__(256) void k_head(
    const float* __restrict__ emb, const float* __restrict__ Wh1,
    const float* __restrict__ bh1, const float* __restrict__ Wh2,
    const float* __restrict__ bh2, float* __restrict__ scores, int N) {
  __shared__ float w1s[64 * 132];
  __shared__ float w2s[64];
  __shared__ float b1s[64];
  int t = threadIdx.x;
  for (int i = t; i < 64 * 32; i += 256) {
    int r = i >> 5, c4 = i & 31;
    float4 v = ((const float4*)Wh1)[i];
    *(float4*)&w1s[r * 132 + c4 * 4] = v;
  }
  if (t < 64) { w2s[t] = Wh2[t]; b1s[t] = bh1[t]; }
  __syncthreads();
  float b2v = bh2[0];
  int wave = t >> 6, lane = t & 63;
  int gw = blockIdx.x * 4 + wave;
  int nw = gridDim.x * 4;
  for (int n = gw; n < N; n += nw) {
    float2 xv = ((const float2*)(emb + (size_t)n * 128))[lane];
    float z = b1s[lane];
#pragma unroll
    for (int j = 0; j < 32; ++j) {
      float4 w = *(const float4*)&w1s[lane * 132 + 4 * j];
      float a0 = __shfl(xv.x, 2 * j);
      float a1 = __shfl(xv.y, 2 * j);
      float a2 = __shfl(xv.x, 2 * j + 1);
      float a3 = __shfl(xv.y, 2 * j + 1);
      z += w.x * a0 + w.y * a1 + w.z * a2 + w.w * a3;
    }
    z = fmaxf(z, 0.f);
    float v = z * w2s[lane];
#pragma unroll
    for (int off = 32; off; off >>= 1) v += __shfl_down(v, off);
    if (lane == 0) scores[n] = 1.f / (1.f + __expf(-(v + b2v)));
  }
}

// ---------------------------------------------------------------------------

extern "C" void kernel_launch(void* const* d_in, const int* in_sizes, int n_in,
                              void* d_out, int out_size, void* d_ws, size_t ws_size,
                              hipStream_t stream) {
  const float* x   = (const float*)d_in[0];
  const int*   ei  = (const int*)d_in[1];
  const float* W1  = (const float*)d_in[2];
  const float* as1 = (const float*)d_in[3];
  const float* ad1 = (const float*)d_in[4];
  const float* b1  = (const float*)d_in[5];
  const float* W2  = (const float*)d_in[6];
  const float* as2 = (const float*)d_in[7];
  const float* ad2 = (const float*)d_in[8];
  const float* b2  = (const float*)d_in[9];
  const float* W3  = (const float*)d_in[10];
  const float* as3 = (const float*)d_in[11];
  const float* ad3 = (const float*)d_in[12];
  const float* b3  = (const float*)d_in[13];
  const float* Wh1 = (const float*)d_in[14];
  const float* bh1 = (const float*)d_in[15];
  const float* Wh2 = (const float*)d_in[16];
  const float* bh2 = (const float*)d_in[17];
  float* out = (float*)d_out;

  const int F = 256, HC = 512, H = 4, C = 128;
  const int N = in_sizes[0] / F;
  const int E = in_sizes[1] / 2;
  const int Et = E + N;
  const int* srcArr = ei;
  const int* dstArr = ei + E;

  char* ws = (char*)d_ws;
  size_t off = 0;
  auto alloc = [&](size_t bytes) -> void* {
    void* p = ws + off;
    off += (bytes + 255) & ~(size_t)255;
    return p;
  };
  f16*   h16    = (f16*)alloc((size_t)N * HC * 2);
  f16*   hAgg   = (f16*)alloc((size_t)N * HC * 2);
  f16*   xh     = (f16*)alloc((size_t)N * F * 2);
  f16*   W1h    = (f16*)alloc((size_t)HC * F * 2);
  f16*   W2h    = (f16*)alloc((size_t)HC * HC * 2);
  f16*   W3h    = (f16*)alloc((size_t)C * HC * 2);
  int* row_ptr  = (int*)alloc((size_t)(N + 1) * 4);
  // zero region: cnt (N ints) + 3x4 gmax uints, one memset
  char* zr      = (char*)alloc((size_t)N * 4 + 64);
  int* cnt      = (int*)zr;
  unsigned* gm1 = (unsigned*)(zr + (size_t)N * 4);
  unsigned* gm2 = gm1 + 4;
  unsigned* gm3 = gm1 + 8;
  int* cursor   = (int*)alloc((size_t)N * 4);
  int* perm     = (int*)alloc((size_t)Et * 4);
  float* sArr   = (float*)alloc((size_t)N * H * 4);
  float* dArr   = (float*)alloc((size_t)N * H * 4);
  int* bsum     = (int*)alloc((size_t)1028 * 4);
  (void)ws_size; (void)n_in; (void)out_size;

  // ---- CSR build ----
  hipMemsetAsync(zr, 0, (size_t)N * 4 + 64, stream);
  int eb = (Et + 255) / 256;
  int nb = (N + 1023) / 1024;
  k_count<<<eb, 256, 0, stream>>>(dstArr, cnt, E, Et);
  k_scanA<<<nb, 256, 0, stream>>>(cnt, row_ptr, bsum, N);
  k_scanB<<<1, 1024, 0, stream>>>(bsum, nb);
  k_scanC<<<(N + 256) / 256, 256, 0, stream>>>(row_ptr, cursor, bsum, N, nb);
  k_fill<<<eb, 256, 0, stream>>>(dstArr, cursor, perm, E, Et);

  // ---- fp16 conversions (one launch) ----
  int c0 = N * F / 4, c1 = HC * F / 4, c2 = HC * HC / 4, c3 = C * HC / 4;
  int ctot = c0 + c1 + c2 + c3;
  k_f2h4<<<(ctot + 255) / 256, 256, 0, stream>>>(x, xh, c0, W1, W1h, c1,
                                                 W2, W2h, c2, W3, W3h, c3);

  int aggGrid = (N + 3) / 4;
  dim3 g1(HC / 128, (N + 127) / 128);
  dim3 g3(C / 128, (N + 127) / 128);

  // ---- layer 1: F -> H*C, elu ----
  k_hgemm_nt<<<g1, 256, 0, stream>>>(xh, W1h, h16, N, HC, F,
                                     as1, ad1, sArr, dArr, gm1, H);
  k_aggregate<4, 512, true, f16><<<aggGrid, 256, 0, stream>>>(
      h16, sArr, dArr, row_ptr, perm, srcArr, gm1, b1, hAgg, N, E);

  // ---- layer 2: H*C -> H*C, elu ----
  k_hgemm_nt<<<g1, 256, 0, stream>>>(hAgg, W2h, h16, N, HC, HC,
                                     as2, ad2, sArr, dArr, gm2, H);
  k_aggregate<4, 512, true, f16><<<aggGrid, 256, 0, stream>>>(
      h16, sArr, dArr, row_ptr, perm, srcArr, gm2, b2, hAgg, N, E);

  // ---- layer 3: H*C -> C, single head, no concat/elu -> embeddings ----
  k_hgemm_nt<<<g3, 256, 0, stream>>>(hAgg, W3h, h16, N, C, HC,
                                     as3, ad3, sArr, dArr, gm3, 1);
  k_aggregate<1, 128, false, float><<<aggGrid, 256, 0, stream>>>(
      h16, sArr, dArr, row_ptr, perm, srcArr, gm3, b3, out, N, E);

  // ---- allocation head ----
  k_head<<<512, 256, 0, stream>>>(out, Wh1, bh1, Wh2, bh2, out + (size_t)N * C, N);
}

// Round 2
// 788.648 us; speedup vs baseline: 1.0733x; 1.0732x over previous
//
#include <hip/hip_runtime.h>
#include <math.h>

typedef _Float16 f16;
typedef f16 f16x2 __attribute__((ext_vector_type(2)));
typedef f16 f16x8 __attribute__((ext_vector_type(8)));
typedef float f32x4 __attribute__((ext_vector_type(4)));

template <int V> struct VecT;
template <> struct VecT<2> { using T = f16 __attribute__((ext_vector_type(2))); };
template <> struct VecT<8> { using T = f16 __attribute__((ext_vector_type(8))); };

__device__ __forceinline__ unsigned ordf(float f) {
  unsigned u = __float_as_uint(f);
  return (u >> 31) ? ~u : (u | 0x80000000u);
}
__device__ __forceinline__ float unordf(unsigned u) {
  return (u >> 31) ? __uint_as_float(u & 0x7fffffffu) : __uint_as_float(~u);
}

// ---------------------------------------------------------------------------
// CSR build: histogram of dst -> 3-stage parallel scan -> fill src-id array
// Edge id space: [0, E) = real edges, [E, E+N) = self loops (src=dst=id-E)
// k_fill resolves src immediately: esrc[pos] = src node id (one less
// indirection per edge per layer in the aggregates).
// ---------------------------------------------------------------------------

__global__ void k_count(const int* __restrict__ dstArr, int* __restrict__ cnt,
                        int E, int Et) {
  int i = blockIdx.x * blockDim.x + threadIdx.x;
  if (i >= Et) return;
  int d = (i < E) ? dstArr[i] : (i - E);
  atomicAdd(&cnt[d], 1);
}

__global__ __launch_bounds__(256) void k_scanA(const int* __restrict__ cnt,
                                               int* __restrict__ row_ptr,
                                               int* __restrict__ bsum, int n) {
  __shared__ int part[256];
  int t = threadIdx.x;
  int base = blockIdx.x * 1024 + t * 4;
  int4 v = make_int4(0, 0, 0, 0);
  if (base + 3 < n) v = *(const int4*)&cnt[base];
  else {
    if (base + 0 < n) v.x = cnt[base + 0];
    if (base + 1 < n) v.y = cnt[base + 1];
    if (base + 2 < n) v.z = cnt[base + 2];
    if (base + 3 < n) v.w = cnt[base + 3];
  }
  int s = v.x + v.y + v.z + v.w;
  part[t] = s;
  __syncthreads();
  for (int off = 1; off < 256; off <<= 1) {
    int x = (t >= off) ? part[t - off] : 0;
    __syncthreads();
    part[t] += x;
    __syncthreads();
  }
  int p0 = (t == 0) ? 0 : part[t - 1];
  int p1 = p0 + v.x, p2 = p1 + v.y, p3 = p2 + v.z;
  if (base + 0 < n) row_ptr[base + 0] = p0;
  if (base + 1 < n) row_ptr[base + 1] = p1;
  if (base + 2 < n) row_ptr[base + 2] = p2;
  if (base + 3 < n) row_ptr[base + 3] = p3;
  if (t == 255) bsum[blockIdx.x] = part[255];
}

__global__ __launch_bounds__(1024) void k_scanB(int* __restrict__ bsum, int nb) {
  __shared__ int part[1024];
  int t = threadIdx.x;
  int v = (t < nb) ? bsum[t] : 0;
  part[t] = v;
  __syncthreads();
  for (int off = 1; off < 1024; off <<= 1) {
    int x = (t >= off) ? part[t - off] : 0;
    __syncthreads();
    part[t] += x;
    __syncthreads();
  }
  if (t < nb) bsum[t] = (t == 0) ? 0 : part[t - 1];
  if (t == 1023) bsum[nb] = part[1023];
}

__global__ void k_scanC(int* __restrict__ row_ptr, int* __restrict__ cursor,
                        const int* __restrict__ bsum, int n, int nb) {
  int i = blockIdx.x * blockDim.x + threadIdx.x;
  if (i < n) {
    int v = row_ptr[i] + bsum[i >> 10];
    row_ptr[i] = v;
    cursor[i] = v;
  }
  if (i == n) row_ptr[n] = bsum[nb];
}

__global__ void k_fill(const int* __restrict__ dstArr,
                       const int* __restrict__ srcArr, int* __restrict__ cursor,
                       int* __restrict__ esrc, int E, int Et) {
  int i = blockIdx.x * blockDim.x + threadIdx.x;
  if (i >= Et) return;
  int d, s;
  if (i < E) { d = dstArr[i]; s = srcArr[i]; }
  else       { d = i - E; s = d; }
  int pos = atomicAdd(&cursor[d], 1);
  esrc[pos] = s;
}

// ---------------------------------------------------------------------------
// fp32 -> fp16 conversion, 4 segments in one launch (each n multiple of 4)
// ---------------------------------------------------------------------------
__global__ void k_f2h4(const float* s0, f16* d0, int n0,
                       const float* s1, f16* d1, int n1,
                       const float* s2, f16* d2, int n2,
                       const float* s3, f16* d3, int n3) {
  int i = blockIdx.x * blockDim.x + threadIdx.x;
  const float* s; f16* d;
  if (i < n0) { s = s0; d = d0; }
  else if ((i -= n0) < n1) { s = s1; d = d1; }
  else if ((i -= n1) < n2) { s = s2; d = d2; }
  else if ((i -= n2) < n3) { s = s3; d = d3; }
  else return;
  float4 v = ((const float4*)s)[i];
  union { f16 h[4]; double dd; } u;
  u.h[0] = (f16)v.x; u.h[1] = (f16)v.y; u.h[2] = (f16)v.z; u.h[3] = (f16)v.w;
  ((double*)d)[i] = u.dd;
}

// ---------------------------------------------------------------------------
// HGEMM (fp16 MFMA, fp32 accumulate): C[M,Nn] = A[M,K] @ B[Nn,K]^T
// 128x128 tile, BK=32, 256 thr = 4 waves, wave = 64x64 quadrant (4x4 MFMAs).
// v3: double-buffered LDS + counted vmcnt pipeline (T3+T4): next tile's
// global_load_lds issued BEFORE this tile's MFMA; per-wave vmcnt(4) (4 loads
// per stage, one stage in flight) instead of a full drain, so HBM latency
// hides under compute + barrier instead of stalling the whole block.
// 1-D grid + bijective XCD-chunk swizzle: the nbx column-blocks sharing an
// A-panel run temporally adjacent on the SAME XCD -> A-panel L2 reuse.
// Fused GAT-attention epilogue (block covers one head's 128 cols).
// ---------------------------------------------------------------------------
__global__ __launch_bounds__(256) void k_hgemm_nt(
    const f16* __restrict__ A, const f16* __restrict__ B,
    f16* __restrict__ C, int M, int Nn, int K, int nbx,
    const float* __restrict__ a_src, const float* __restrict__ a_dst,
    float* __restrict__ sArr, float* __restrict__ dArr,
    unsigned* __restrict__ gmaxU, int H) {
  __shared__ f16 As[2 * 128 * 32];
  __shared__ f16 Bs[2 * 128 * 32];
  int tid = threadIdx.x;
  int wave = tid >> 6, lane = tid & 63;
  int quad = lane >> 4, l16 = lane & 15;

  // ---- XCD-chunk swizzle (bijective, m204 form) ----
  int nwg = gridDim.x;
  int orig = blockIdx.x;
  int q = nwg >> 3, r = nwg & 7;
  int xcd = orig & 7, pos = orig >> 3;
  int swz = (xcd < r) ? (xcd * (q + 1) + pos)
                      : (r * (q + 1) + (xcd - r) * q + pos);
  int bx = swz % nbx;
  int by = swz / nbx;
  int m0 = by * 128, n0 = bx * 128;
  int wm = (wave & 1) * 64, wn = (wave >> 1) * 64;

  // ---- staging addresses (wave w stages rows w*16.. and 64+w*16.. of A and B)
  int lr = lane >> 2;            // row within 16-row group
  int lc = lane & 3;             // lds chunk slot this lane fills
  int chunk = lc ^ ((lr >> 1) & 3);  // global chunk to fetch (swizzle)
  int rb0 = wave * 16;
  int rb1 = 64 + wave * 16;
  int ga0 = m0 + rb0 + lr; if (ga0 >= M) ga0 = M - 1;
  int ga1 = m0 + rb1 + lr; if (ga1 >= M) ga1 = M - 1;
  const f16* gA0 = A + (size_t)ga0 * K + chunk * 8;
  const f16* gA1 = A + (size_t)ga1 * K + chunk * 8;
  const f16* gB0 = B + (size_t)(n0 + rb0 + lr) * K + chunk * 8;
  const f16* gB1 = B + (size_t)(n0 + rb1 + lr) * K + chunk * 8;

  // ---- fragment read pointers (chunk = quad ^ ((l16>>1)&3))
  int rsw = (quad ^ ((l16 >> 1) & 3)) * 8;
  const f16* Ard[4];
  const f16* Brd[4];
#pragma unroll
  for (int i = 0; i < 4; ++i) {
    Ard[i] = &As[(wm + i * 16 + l16) * 32 + rsw];
    Brd[i] = &Bs[(wn + i * 16 + l16) * 32 + rsw];
  }

  f32x4 acc[4][4];
#pragma unroll
  for (int i = 0; i < 4; ++i)
#pragma unroll
    for (int j = 0; j < 4; ++j) acc[i][j] = (f32x4)(0.f);

#define GLDS(gp, lp)                                                     \
  __builtin_amdgcn_global_load_lds(                                      \
      (const __attribute__((address_space(1))) void*)(gp),               \
      (__attribute__((address_space(3))) void*)(lp), 16, 0, 0)
#define STAGE(buf, kk)                                                   \
  do {                                                                   \
    GLDS(gA0 + (kk), As + (buf) * 4096 + rb0 * 32);                      \
    GLDS(gA1 + (kk), As + (buf) * 4096 + rb1 * 32);                      \
    GLDS(gB0 + (kk), Bs + (buf) * 4096 + rb0 * 32);                      \
    GLDS(gB1 + (kk), Bs + (buf) * 4096 + rb1 * 32);                      \
  } while (0)

  int nt = K >> 5;
  STAGE(0, 0);
  for (int t = 0; t < nt; ++t) {
    int cur = t & 1;
    if (t + 1 < nt) {
      STAGE(cur ^ 1, (t + 1) << 5);
      // 8 loads outstanding; wait to 4 -> tile t's 4 have landed (this wave)
      asm volatile("s_waitcnt vmcnt(4)\n\ts_barrier" ::: "memory");
    } else {
      asm volatile("s_waitcnt vmcnt(0)\n\ts_barrier" ::: "memory");
    }
    f16x8 af[4], bf[4];
#pragma unroll
    for (int i = 0; i < 4; ++i) af[i] = *(const f16x8*)(Ard[i] + cur * 4096);
#pragma unroll
    for (int j = 0; j < 4; ++j) bf[j] = *(const f16x8*)(Brd[j] + cur * 4096);
#pragma unroll
    for (int i = 0; i < 4; ++i)
#pragma unroll
      for (int j = 0; j < 4; ++j)
        acc[i][j] = __builtin_amdgcn_mfma_f32_16x16x32_f16(af[i], bf[j], acc[i][j], 0, 0, 0);
    // frag ds_reads of buf[cur] complete (consumed by MFMA); sync before
    // next iteration's STAGE overwrites buf[cur]
    asm volatile("s_barrier" ::: "memory");
  }
#undef STAGE
#undef GLDS

  // ---- C store ----
#pragma unroll
  for (int i = 0; i < 4; ++i) {
#pragma unroll
    for (int r = 0; r < 4; ++r) {
      int m = m0 + wm + i * 16 + quad * 4 + r;
      if (m < M) {
        f16* Cp = C + (size_t)m * Nn + n0 + wn + l16;
#pragma unroll
        for (int j = 0; j < 4; ++j) Cp[j * 16] = (f16)acc[i][j][r];
      }
    }
  }

  // ---- fused attention scalars ----
  float av[4], ad[4];
#pragma unroll
  for (int j = 0; j < 4; ++j) {
    int col = n0 + wn + l16 + j * 16;
    av[j] = a_src[col];
    ad[j] = a_dst[col];
  }
  float sp[16], dp[16];
#pragma unroll
  for (int i = 0; i < 4; ++i)
#pragma unroll
    for (int r = 0; r < 4; ++r) {
      float ss = 0.f, dd = 0.f;
#pragma unroll
      for (int j = 0; j < 4; ++j) {
        ss += acc[i][j][r] * av[j];
        dd += acc[i][j][r] * ad[j];
      }
#pragma unroll
      for (int msk = 1; msk < 16; msk <<= 1) {
        ss += __shfl_xor(ss, msk);
        dd += __shfl_xor(dd, msk);
      }
      sp[i * 4 + r] = ss;
      dp[i * 4 + r] = dd;
    }

  __syncthreads();  // done reading As/Bs; reuse as float scratch
  float* fb = (float*)As;
  int wv = wn >> 6;
  if (l16 == 0) {
#pragma unroll
    for (int i = 0; i < 4; ++i)
#pragma unroll
      for (int r = 0; r < 4; ++r) {
        int row = wm + i * 16 + quad * 4 + r;
        fb[wv * 128 + row] = sp[i * 4 + r];
        fb[256 + wv * 128 + row] = dp[i * 4 + r];
      }
  }
  __syncthreads();
  if (tid < 128) {
    int m = m0 + tid;
    if (m < M) {
      float s = fb[tid] + fb[128 + tid];
      float d = fb[256 + tid] + fb[384 + tid];
      int head = n0 >> 7;
      sArr[(size_t)m * H + head] = s;
      dArr[(size_t)m * H + head] = d;
      atomicMax(&gmaxU[head], ordf(s));
    }
  }
}

// ---------------------------------------------------------------------------
// Segment softmax + aggregation: ONE WAVE PER NODE, no barriers.
// v3: esrc array holds resolved src ids (2-hop chain instead of 3); per-chunk
// (soff, w) pairs staged head-major in LDS (int2 stores at stride 8 B = 2-way
// bank alias = free; v2's int4 layout was 16-way). Inner loop: 1 ds_read_b64
// per edge + pipelined 16B gathers, groups of 4 edges, double-buffered.
// Shift = leaky(gmax + d_n) >= segment max (leaky monotone; softmax
// shift-invariant). gmax passed as order-preserving uint.
// ---------------------------------------------------------------------------
template <int HH, int CT, bool DOELU, typename OutT>
__global__ __launch_bounds__(256) void k_aggregate(
    const f16* __restrict__ hin, const float* __restrict__ sArr,
    const float* __restrict__ dArr, const int* __restrict__ row_ptr,
    const int* __restrict__ esrc, const unsigned* __restrict__ gmaxU,
    const float* __restrict__ bias, OutT* __restrict__ outp, int N, int E) {
  constexpr int VEC = CT / 64;
  constexpr int CPER = CT / HH;
  using gvec = typename VecT<VEC>::T;

  __shared__ int2 pairs[4][HH * 64];  // [wave][h*64 + edge] = {soff, w_h}

  int wave = threadIdx.x >> 6;
  int lane = threadIdx.x & 63;
  int n = blockIdx.x * 4 + wave;
  if (n >= N) return;
  int e0 = row_ptr[n];
  int deg = row_ptr[n + 1] - e0;

  const int myhead = (HH == 1) ? 0 : (lane * VEC) / CPER;
  const int laneByte = lane * VEC * 2;

  float dloc[HH], mn[HH];
#pragma unroll
  for (int h = 0; h < HH; ++h) {
    dloc[h] = dArr[n * HH + h];
    float m = unordf(gmaxU[h]) + dloc[h];
    mn[h] = (m > 0.f) ? m : 0.2f * m;
  }

  float acc[VEC];
#pragma unroll
  for (int k = 0; k < VEC; ++k) acc[k] = 0.f;
  float dsum[HH];
#pragma unroll
  for (int h = 0; h < HH; ++h) dsum[h] = 0.f;

  int2* pw = &pairs[wave][0];
  const int2* pr = &pairs[wave][myhead * 64];

#define LOADG(VB, WB, g)                                                      \
  do {                                                                        \
    _Pragma("unroll") for (int j_ = 0; j_ < 4; ++j_) {                        \
      int2 p_ = pr[(g) * 4 + j_];                                             \
      WB[j_] = __int_as_float(p_.y);                                          \
      VB[j_] = *(const gvec*)((const char*)hin + (unsigned)(p_.x + laneByte));\
    }                                                                         \
  } while (0)

#define FMAG(VB, WB)                                                          \
  do {                                                                        \
    _Pragma("unroll") for (int j_ = 0; j_ < 4; ++j_)                          \
        _Pragma("unroll") for (int k_ = 0; k_ < VEC; ++k_)                    \
            acc[k_] += WB[j_] * (float)VB[j_][k_];                            \
  } while (0)

  for (int base = 0; base < deg; base += 64) {
    int cn = min(64, deg - base);

    // ---- producer phase: this lane's edge -> (soff, w[h]) ----
    int soff = 0;
    float w_l[HH];
#pragma unroll
    for (int h = 0; h < HH; ++h) w_l[h] = 0.f;
    if (lane < cn) {
      int s = esrc[e0 + base + lane];
      soff = s * (CT * 2);
      if (HH == 4) {
        float4 sv = ((const float4*)sArr)[s];
        float svv[4] = {sv.x, sv.y, sv.z, sv.w};
#pragma unroll
        for (int h = 0; h < 4; ++h) {
          float e = svv[h] + dloc[h];
          e = (e > 0.f) ? e : 0.2f * e;
          w_l[h] = __expf(e - mn[h]);
        }
      } else {
        float e = sArr[s] + dloc[0];
        e = (e > 0.f) ? e : 0.2f * e;
        w_l[0] = __expf(e - mn[0]);
      }
    }
#pragma unroll
    for (int h = 0; h < HH; ++h) dsum[h] += w_l[h];

#pragma unroll
    for (int h = 0; h < HH; ++h)
      pw[h * 64 + lane] = make_int2(soff, __float_as_int(w_l[h]));
    // same-wave LDS visibility: drain DS queue; "memory" clobber orders the
    // surrounding ds_write/ds_read (no cross-wave sharing -> no s_barrier)
    asm volatile("s_waitcnt lgkmcnt(0)" ::: "memory");

    // ---- consumer phase: pipelined gather+FMA, groups of 4 edges ----
    int cng = (cn + 3) >> 2;  // tail edges padded with w=0 by producer
    gvec vA[4], vB[4];
    float wA[4], wB[4];
    LOADG(vA, wA, 0);
    int g = 0;
    while (g + 2 < cng) {
      LOADG(vB, wB, g + 1);
      FMAG(vA, wA);
      LOADG(vA, wA, g + 2);
      FMAG(vB, wB);
      g += 2;
    }
    if (g + 1 < cng) {
      LOADG(vB, wB, g + 1);
      FMAG(vA, wA);
      FMAG(vB, wB);
    } else {
      FMAG(vA, wA);
    }
  }
#undef LOADG
#undef FMAG

  // ---- denominator: one wave reduction per head, then per-lane select ----
  float dn;
  if (HH == 4) {
    float t0 = dsum[0], t1 = dsum[1], t2 = dsum[2], t3 = dsum[3];
#pragma unroll
    for (int m = 1; m < 64; m <<= 1) {
      t0 += __shfl_xor(t0, m);
      t1 += __shfl_xor(t1, m);
      t2 += __shfl_xor(t2, m);
      t3 += __shfl_xor(t3, m);
    }
    dn = (myhead < 2) ? (myhead == 0 ? t0 : t1) : (myhead == 2 ? t2 : t3);
  } else {
    float t0 = dsum[0];
#pragma unroll
    for (int m = 1; m < 64; m <<= 1) t0 += __shfl_xor(t0, m);
    dn = t0;
  }
  dn += 1e-16f;

  struct alignas(sizeof(OutT) * VEC) OutV { OutT v[VEC]; } ov;
#pragma unroll
  for (int k = 0; k < VEC; ++k) {
    float v = acc[k] / dn + bias[lane * VEC + k];
    if (DOELU) v = (v > 0.f) ? v : expm1f(v);
    ov.v[k] = (OutT)v;
  }
  *(OutV*)(outp + (size_t)n * CT + lane * VEC) = ov;
}

// ---------------------------------------------------------------------------
// Allocation head (Wh1 staged in LDS, persistent blocks)
// ---------------------------------------------------------------------------
__global__ __launch_bounds__(256) void k_head(
    const float* __restrict__ emb, const float* __restrict__ Wh1,
    const float* __restrict__ bh1, const float* __restrict__ Wh2,
    const float* __restrict__ bh2, float* __restrict__ scores, int N) {
  __shared__ float w1s[64 * 132];
  __shared__ float w2s[64];
  __shared__ float b1s[64];
  int t = threadIdx.x;
  for (int i = t; i < 64 * 32; i += 256) {
    int r = i >> 5, c4 = i & 31;
    float4 v = ((const float4*)Wh1)[i];
    *(float4*)&w1s[r * 132 + c4 * 4] = v;
  }
  if (t < 64) { w2s[t] = Wh2[t]; b1s[t] = bh1[t]; }
  __syncthreads();
  float b2v = bh2[0];
  int wave = t >> 6, lane = t & 63;
  int gw = blockIdx.x * 4 + wave;
  int nw = gridDim.x * 4;
  for (int n = gw; n < N; n += nw) {
    float2 xv = ((const float2*)(emb + (size_t)n * 128))[lane];
    float z = b1s[lane];
#pragma unroll
    for (int j = 0; j < 32; ++j) {
      float4 w = *(const float4*)&w1s[lane * 132 + 4 * j];
      float a0 = __shfl(xv.x, 2 * j);
      float a1 = __shfl(xv.y, 2 * j);
      float a2 = __shfl(xv.x, 2 * j + 1);
      float a3 = __shfl(xv.y, 2 * j + 1);
      z += w.x * a0 + w.y * a1 + w.z * a2 + w.w * a3;
    }
    z = fmaxf(z, 0.f);
    float v = z * w2s[lane];
#pragma unroll
    for (int off = 32; off; off >>= 1) v += __shfl_down(v, off);
    if (lane == 0) scores[n] = 1.f / (1.f + __expf(-(v + b2v)));
  }
}

// ---------------------------------------------------------------------------

extern "C" void kernel_launch(void* const* d_in, const int* in_sizes, int n_in,
                              void* d_out, int out_size, void* d_ws, size_t ws_size,
                              hipStream_t stream) {
  const float* x   = (const float*)d_in[0];
  const int*   ei  = (const int*)d_in[1];
  const float* W1  = (const float*)d_in[2];
  const float* as1 = (const float*)d_in[3];
  const float* ad1 = (const float*)d_in[4];
  const float* b1  = (const float*)d_in[5];
  const float* W2  = (const float*)d_in[6];
  const float* as2 = (const float*)d_in[7];
  const float* ad2 = (const float*)d_in[8];
  const float* b2  = (const float*)d_in[9];
  const float* W3  = (const float*)d_in[10];
  const float* as3 = (const float*)d_in[11];
  const float* ad3 = (const float*)d_in[12];
  const float* b3  = (const float*)d_in[13];
  const float* Wh1 = (const float*)d_in[14];
  const float* bh1 = (const float*)d_in[15];
  const float* Wh2 = (const float*)d_in[16];
  const float* bh2 = (const float*)d_in[17];
  float* out = (float*)d_out;

  const int F = 256, HC = 512, H = 4, C = 128;
  const int N = in_sizes[0] / F;
  const int E = in_sizes[1] / 2;
  const int Et = E + N;
  const int* srcArr = ei;
  const int* dstArr = ei + E;

  char* ws = (char*)d_ws;
  size_t off = 0;
  auto alloc = [&](size_t bytes) -> void* {
    void* p = ws + off;
    off += (bytes + 255) & ~(size_t)255;
    return p;
  };
  f16*   h16    = (f16*)alloc((size_t)N * HC * 2);
  f16*   hAgg   = (f16*)alloc((size_t)N * HC * 2);
  f16*   xh     = (f16*)alloc((size_t)N * F * 2);
  f16*   W1h    = (f16*)alloc((size_t)HC * F * 2);
  f16*   W2h    = (f16*)alloc((size_t)HC * HC * 2);
  f16*   W3h    = (f16*)alloc((size_t)C * HC * 2);
  int* row_ptr  = (int*)alloc((size_t)(N + 1) * 4);
  // zero region: cnt (N ints) + 3x4 gmax uints, one memset
  char* zr      = (char*)alloc((size_t)N * 4 + 64);
  int* cnt      = (int*)zr;
  unsigned* gm1 = (unsigned*)(zr + (size_t)N * 4);
  unsigned* gm2 = gm1 + 4;
  unsigned* gm3 = gm1 + 8;
  int* cursor   = (int*)alloc((size_t)N * 4);
  int* esrc     = (int*)alloc((size_t)Et * 4);
  float* sArr   = (float*)alloc((size_t)N * H * 4);
  float* dArr   = (float*)alloc((size_t)N * H * 4);
  int* bsum     = (int*)alloc((size_t)1028 * 4);
  (void)ws_size; (void)n_in; (void)out_size;

  // ---- CSR build ----
  hipMemsetAsync(zr, 0, (size_t)N * 4 + 64, stream);
  int eb = (Et + 255) / 256;
  int nb = (N + 1023) / 1024;
  k_count<<<eb, 256, 0, stream>>>(dstArr, cnt, E, Et);
  k_scanA<<<nb, 256, 0, stream>>>(cnt, row_ptr, bsum, N);
  k_scanB<<<1, 1024, 0, stream>>>(bsum, nb);
  k_scanC<<<(N + 256) / 256, 256, 0, stream>>>(row_ptr, cursor, bsum, N, nb);
  k_fill<<<eb, 256, 0, stream>>>(dstArr, srcArr, cursor, esrc, E, Et);

  // ---- fp16 conversions (one launch) ----
  int c0 = N * F / 4, c1 = HC * F / 4, c2 = HC * HC / 4, c3 = C * HC / 4;
  int ctot = c0 + c1 + c2 + c3;
  k_f2h4<<<(ctot + 255) / 256, 256, 0, stream>>>(x, xh, c0, W1, W1h, c1,
                                                 W2, W2h, c2, W3, W3h, c3);

  int aggGrid = (N + 3) / 4;
  int mblk = (N + 127) / 128;
  int nblk1 = 4 * mblk;   // layers 1,2: nbx=4
  int nblk3 = mblk;       // layer 3:    nbx=1

  // ---- layer 1: F -> H*C, elu ----
  k_hgemm_nt<<<nblk1, 256, 0, stream>>>(xh, W1h, h16, N, HC, F, 4,
                                        as1, ad1, sArr, dArr, gm1, H);
  k_aggregate<4, 512, true, f16><<<aggGrid, 256, 0, stream>>>(
      h16, sArr, dArr, row_ptr, esrc, gm1, b1, hAgg, N, E);

  // ---- layer 2: H*C -> H*C, elu ----
  k_hgemm_nt<<<nblk1, 256, 0, stream>>>(hAgg, W2h, h16, N, HC, HC, 4,
                                        as2, ad2, sArr, dArr, gm2, H);
  k_aggregate<4, 512, true, f16><<<aggGrid, 256, 0, stream>>>(
      h16, sArr, dArr, row_ptr, esrc, gm2, b2, hAgg, N, E);

  // ---- layer 3: H*C -> C, single head, no concat/elu -> embeddings ----
  k_hgemm_nt<<<nblk3, 256, 0, stream>>>(hAgg, W3h, h16, N, C, HC, 1,
                                        as3, ad3, sArr, dArr, gm3, 1);
  k_aggregate<1, 128, false, float><<<aggGrid, 256, 0, stream>>>(
      h16, sArr, dArr, row_ptr, esrc, gm3, b3, out, N, E);

  // ---- allocation head ----
  k_head<<<512, 256, 0, stream>>>(out, Wh1, bh1, Wh2, bh2, out + (size_t)N * C, N);
}

// Round 3
// 759.062 us; speedup vs baseline: 1.1151x; 1.0390x over previous
//
#include <hip/hip_runtime.h>
#include <math.h>

typedef _Float16 f16;
typedef f16 f16x2 __attribute__((ext_vector_type(2)));
typedef f16 f16x8 __attribute__((ext_vector_type(8)));
typedef float f32x4 __attribute__((ext_vector_type(4)));

template <int V> struct VecT;
template <> struct VecT<2> { using T = f16 __attribute__((ext_vector_type(2))); };
template <> struct VecT<8> { using T = f16 __attribute__((ext_vector_type(8))); };

__device__ __forceinline__ unsigned ordf(float f) {
  unsigned u = __float_as_uint(f);
  return (u >> 31) ? ~u : (u | 0x80000000u);
}
__device__ __forceinline__ float unordf(unsigned u) {
  return (u >> 31) ? __uint_as_float(u & 0x7fffffffu) : __uint_as_float(~u);
}

// ---------------------------------------------------------------------------
// CSR build: histogram of dst -> 3-stage parallel scan -> fill src-id array
// Edge id space: [0, E) = real edges, [E, E+N) = self loops (src=dst=id-E)
// ---------------------------------------------------------------------------

__global__ void k_count(const int* __restrict__ dstArr, int* __restrict__ cnt,
                        int E, int Et) {
  int i = blockIdx.x * blockDim.x + threadIdx.x;
  if (i >= Et) return;
  int d = (i < E) ? dstArr[i] : (i - E);
  atomicAdd(&cnt[d], 1);
}

__global__ __launch_bounds__(256) void k_scanA(const int* __restrict__ cnt,
                                               int* __restrict__ row_ptr,
                                               int* __restrict__ bsum, int n) {
  __shared__ int part[256];
  int t = threadIdx.x;
  int base = blockIdx.x * 1024 + t * 4;
  int4 v = make_int4(0, 0, 0, 0);
  if (base + 3 < n) v = *(const int4*)&cnt[base];
  else {
    if (base + 0 < n) v.x = cnt[base + 0];
    if (base + 1 < n) v.y = cnt[base + 1];
    if (base + 2 < n) v.z = cnt[base + 2];
    if (base + 3 < n) v.w = cnt[base + 3];
  }
  int s = v.x + v.y + v.z + v.w;
  part[t] = s;
  __syncthreads();
  for (int off = 1; off < 256; off <<= 1) {
    int x = (t >= off) ? part[t - off] : 0;
    __syncthreads();
    part[t] += x;
    __syncthreads();
  }
  int p0 = (t == 0) ? 0 : part[t - 1];
  int p1 = p0 + v.x, p2 = p1 + v.y, p3 = p2 + v.z;
  if (base + 0 < n) row_ptr[base + 0] = p0;
  if (base + 1 < n) row_ptr[base + 1] = p1;
  if (base + 2 < n) row_ptr[base + 2] = p2;
  if (base + 3 < n) row_ptr[base + 3] = p3;
  if (t == 255) bsum[blockIdx.x] = part[255];
}

__global__ __launch_bounds__(1024) void k_scanB(int* __restrict__ bsum, int nb) {
  __shared__ int part[1024];
  int t = threadIdx.x;
  int v = (t < nb) ? bsum[t] : 0;
  part[t] = v;
  __syncthreads();
  for (int off = 1; off < 1024; off <<= 1) {
    int x = (t >= off) ? part[t - off] : 0;
    __syncthreads();
    part[t] += x;
    __syncthreads();
  }
  if (t < nb) bsum[t] = (t == 0) ? 0 : part[t - 1];
  if (t == 1023) bsum[nb] = part[1023];
}

__global__ void k_scanC(int* __restrict__ row_ptr, int* __restrict__ cursor,
                        const int* __restrict__ bsum, int n, int nb) {
  int i = blockIdx.x * blockDim.x + threadIdx.x;
  if (i < n) {
    int v = row_ptr[i] + bsum[i >> 10];
    row_ptr[i] = v;
    cursor[i] = v;
  }
  if (i == n) row_ptr[n] = bsum[nb];
}

__global__ void k_fill(const int* __restrict__ dstArr,
                       const int* __restrict__ srcArr, int* __restrict__ cursor,
                       int* __restrict__ esrc, int E, int Et) {
  int i = blockIdx.x * blockDim.x + threadIdx.x;
  if (i >= Et) return;
  int d, s;
  if (i < E) { d = dstArr[i]; s = srcArr[i]; }
  else       { d = i - E; s = d; }
  int pos = atomicAdd(&cursor[d], 1);
  esrc[pos] = s;
}

// ---------------------------------------------------------------------------
// fp32 -> fp16 conversion, 4 segments in one launch (each n multiple of 4)
// ---------------------------------------------------------------------------
__global__ void k_f2h4(const float* s0, f16* d0, int n0,
                       const float* s1, f16* d1, int n1,
                       const float* s2, f16* d2, int n2,
                       const float* s3, f16* d3, int n3) {
  int i = blockIdx.x * blockDim.x + threadIdx.x;
  const float* s; f16* d;
  if (i < n0) { s = s0; d = d0; }
  else if ((i -= n0) < n1) { s = s1; d = d1; }
  else if ((i -= n1) < n2) { s = s2; d = d2; }
  else if ((i -= n2) < n3) { s = s3; d = d3; }
  else return;
  float4 v = ((const float4*)s)[i];
  union { f16 h[4]; double dd; } u;
  u.h[0] = (f16)v.x; u.h[1] = (f16)v.y; u.h[2] = (f16)v.z; u.h[3] = (f16)v.w;
  ((double*)d)[i] = u.dd;
}

// ---------------------------------------------------------------------------
// HGEMM (fp16 MFMA, fp32 accumulate): C[M,Nn] = A[M,K] @ B[Nn,K]^T
// 128x128 tile, BK=32, 256 thr = 4 waves, wave = 64x64 quadrant (4x4 MFMAs).
// Double-buffered LDS + counted vmcnt pipeline (T3+T4); bijective XCD-chunk
// swizzle for A-panel L2 reuse. Fused GAT-attention epilogue.
// v4: global max via block-level reduction -> ONE atomicMax per block per
// head (was one per ROW = 50K same-address device atomics per layer, which
// serialize at a single L2 bank and dominated the GEMM dispatch time).
// ---------------------------------------------------------------------------
__global__ __launch_bounds__(256) void k_hgemm_nt(
    const f16* __restrict__ A, const f16* __restrict__ B,
    f16* __restrict__ C, int M, int Nn, int K, int nbx,
    const float* __restrict__ a_src, const float* __restrict__ a_dst,
    float* __restrict__ sArr, float* __restrict__ dArr,
    unsigned* __restrict__ gmaxU, int H) {
  __shared__ f16 As[2 * 128 * 32];
  __shared__ f16 Bs[2 * 128 * 32];
  int tid = threadIdx.x;
  int wave = tid >> 6, lane = tid & 63;
  int quad = lane >> 4, l16 = lane & 15;

  // ---- XCD-chunk swizzle (bijective, m204 form) ----
  int nwg = gridDim.x;
  int orig = blockIdx.x;
  int q = nwg >> 3, r = nwg & 7;
  int xcd = orig & 7, pos = orig >> 3;
  int swz = (xcd < r) ? (xcd * (q + 1) + pos)
                      : (r * (q + 1) + (xcd - r) * q + pos);
  int bx = swz % nbx;
  int by = swz / nbx;
  int m0 = by * 128, n0 = bx * 128;
  int wm = (wave & 1) * 64, wn = (wave >> 1) * 64;

  // ---- staging addresses (wave w stages rows w*16.. and 64+w*16.. of A and B)
  int lr = lane >> 2;            // row within 16-row group
  int lc = lane & 3;             // lds chunk slot this lane fills
  int chunk = lc ^ ((lr >> 1) & 3);  // global chunk to fetch (swizzle)
  int rb0 = wave * 16;
  int rb1 = 64 + wave * 16;
  int ga0 = m0 + rb0 + lr; if (ga0 >= M) ga0 = M - 1;
  int ga1 = m0 + rb1 + lr; if (ga1 >= M) ga1 = M - 1;
  const f16* gA0 = A + (size_t)ga0 * K + chunk * 8;
  const f16* gA1 = A + (size_t)ga1 * K + chunk * 8;
  const f16* gB0 = B + (size_t)(n0 + rb0 + lr) * K + chunk * 8;
  const f16* gB1 = B + (size_t)(n0 + rb1 + lr) * K + chunk * 8;

  // ---- fragment read pointers (chunk = quad ^ ((l16>>1)&3))
  int rsw = (quad ^ ((l16 >> 1) & 3)) * 8;
  const f16* Ard[4];
  const f16* Brd[4];
#pragma unroll
  for (int i = 0; i < 4; ++i) {
    Ard[i] = &As[(wm + i * 16 + l16) * 32 + rsw];
    Brd[i] = &Bs[(wn + i * 16 + l16) * 32 + rsw];
  }

  f32x4 acc[4][4];
#pragma unroll
  for (int i = 0; i < 4; ++i)
#pragma unroll
    for (int j = 0; j < 4; ++j) acc[i][j] = (f32x4)(0.f);

#define GLDS(gp, lp)                                                     \
  __builtin_amdgcn_global_load_lds(                                      \
      (const __attribute__((address_space(1))) void*)(gp),               \
      (__attribute__((address_space(3))) void*)(lp), 16, 0, 0)
#define STAGE(buf, kk)                                                   \
  do {                                                                   \
    GLDS(gA0 + (kk), As + (buf) * 4096 + rb0 * 32);                      \
    GLDS(gA1 + (kk), As + (buf) * 4096 + rb1 * 32);                      \
    GLDS(gB0 + (kk), Bs + (buf) * 4096 + rb0 * 32);                      \
    GLDS(gB1 + (kk), Bs + (buf) * 4096 + rb1 * 32);                      \
  } while (0)

  int nt = K >> 5;
  STAGE(0, 0);
  for (int t = 0; t < nt; ++t) {
    int cur = t & 1;
    if (t + 1 < nt) {
      STAGE(cur ^ 1, (t + 1) << 5);
      // 8 loads outstanding; wait to 4 -> tile t's 4 have landed (this wave)
      asm volatile("s_waitcnt vmcnt(4)\n\ts_barrier" ::: "memory");
    } else {
      asm volatile("s_waitcnt vmcnt(0)\n\ts_barrier" ::: "memory");
    }
    f16x8 af[4], bf[4];
#pragma unroll
    for (int i = 0; i < 4; ++i) af[i] = *(const f16x8*)(Ard[i] + cur * 4096);
#pragma unroll
    for (int j = 0; j < 4; ++j) bf[j] = *(const f16x8*)(Brd[j] + cur * 4096);
#pragma unroll
    for (int i = 0; i < 4; ++i)
#pragma unroll
      for (int j = 0; j < 4; ++j)
        acc[i][j] = __builtin_amdgcn_mfma_f32_16x16x32_f16(af[i], bf[j], acc[i][j], 0, 0, 0);
    // frag ds_reads of buf[cur] complete (consumed by MFMA); sync before
    // next iteration's STAGE overwrites buf[cur]
    asm volatile("s_barrier" ::: "memory");
  }
#undef STAGE
#undef GLDS

  // ---- C store ----
#pragma unroll
  for (int i = 0; i < 4; ++i) {
#pragma unroll
    for (int r = 0; r < 4; ++r) {
      int m = m0 + wm + i * 16 + quad * 4 + r;
      if (m < M) {
        f16* Cp = C + (size_t)m * Nn + n0 + wn + l16;
#pragma unroll
        for (int j = 0; j < 4; ++j) Cp[j * 16] = (f16)acc[i][j][r];
      }
    }
  }

  // ---- fused attention scalars ----
  float av[4], ad[4];
#pragma unroll
  for (int j = 0; j < 4; ++j) {
    int col = n0 + wn + l16 + j * 16;
    av[j] = a_src[col];
    ad[j] = a_dst[col];
  }
  float sp[16], dp[16];
#pragma unroll
  for (int i = 0; i < 4; ++i)
#pragma unroll
    for (int r = 0; r < 4; ++r) {
      float ss = 0.f, dd = 0.f;
#pragma unroll
      for (int j = 0; j < 4; ++j) {
        ss += acc[i][j][r] * av[j];
        dd += acc[i][j][r] * ad[j];
      }
#pragma unroll
      for (int msk = 1; msk < 16; msk <<= 1) {
        ss += __shfl_xor(ss, msk);
        dd += __shfl_xor(dd, msk);
      }
      sp[i * 4 + r] = ss;
      dp[i * 4 + r] = dd;
    }

  __syncthreads();  // done reading As/Bs; reuse as float scratch
  float* fb = (float*)As;
  int wv = wn >> 6;
  if (l16 == 0) {
#pragma unroll
    for (int i = 0; i < 4; ++i)
#pragma unroll
      for (int r = 0; r < 4; ++r) {
        int row = wm + i * 16 + quad * 4 + r;
        fb[wv * 128 + row] = sp[i * 4 + r];
        fb[256 + wv * 128 + row] = dp[i * 4 + r];
      }
  }
  __syncthreads();
  float sval = -3.0e38f;
  if (tid < 128) {
    int m = m0 + tid;
    if (m < M) {
      float s = fb[tid] + fb[128 + tid];
      float d = fb[256 + tid] + fb[384 + tid];
      int head = n0 >> 7;
      sArr[(size_t)m * H + head] = s;
      dArr[(size_t)m * H + head] = d;
      sval = s;
    }
  }
  // block max -> single atomic (waves 2,3 contribute -inf)
  float mx = sval;
#pragma unroll
  for (int msk = 32; msk; msk >>= 1) mx = fmaxf(mx, __shfl_xor(mx, msk));
  __syncthreads();
  if (lane == 0) fb[512 + wave] = mx;
  __syncthreads();
  if (tid == 0) {
    float m01 = fmaxf(fb[512], fb[513]);
    atomicMax(&gmaxU[n0 >> 7], ordf(m01));
  }
}

// ---------------------------------------------------------------------------
// Segment softmax + aggregation: ONE WAVE PER NODE, no barriers.
// esrc holds resolved src ids; per-chunk (soff, w) pairs staged head-major
// in LDS, stride 66 (pad kills the 4-way head-stride bank conflict on both
// the b64 writes and the per-group broadcast reads). Inner loop: 1
// ds_read_b64 per edge + pipelined 16B gathers, groups of 4, double-buffered.
// Shift = leaky(gmax + d_n) >= segment max (leaky monotone; softmax
// shift-invariant). gmax passed as order-preserving uint.
// ---------------------------------------------------------------------------
template <int HH, int CT, bool DOELU, typename OutT>
__global__ __launch_bounds__(256) void k_aggregate(
    const f16* __restrict__ hin, const float* __restrict__ sArr,
    const float* __restrict__ dArr, const int* __restrict__ row_ptr,
    const int* __restrict__ esrc, const unsigned* __restrict__ gmaxU,
    const float* __restrict__ bias, OutT* __restrict__ outp, int N, int E) {
  constexpr int VEC = CT / 64;
  constexpr int CPER = CT / HH;
  using gvec = typename VecT<VEC>::T;

  __shared__ int2 pairs[4][HH * 66];  // [wave][h*66 + edge] = {soff, w_h}

  int wave = threadIdx.x >> 6;
  int lane = threadIdx.x & 63;
  int n = blockIdx.x * 4 + wave;
  if (n >= N) return;
  int e0 = row_ptr[n];
  int deg = row_ptr[n + 1] - e0;

  const int myhead = (HH == 1) ? 0 : (lane * VEC) / CPER;
  const int laneByte = lane * VEC * 2;

  float dloc[HH], mn[HH];
#pragma unroll
  for (int h = 0; h < HH; ++h) {
    dloc[h] = dArr[n * HH + h];
    float m = unordf(gmaxU[h]) + dloc[h];
    mn[h] = (m > 0.f) ? m : 0.2f * m;
  }

  float acc[VEC];
#pragma unroll
  for (int k = 0; k < VEC; ++k) acc[k] = 0.f;
  float dsum[HH];
#pragma unroll
  for (int h = 0; h < HH; ++h) dsum[h] = 0.f;

  int2* pw = &pairs[wave][0];
  const int2* pr = &pairs[wave][myhead * 66];

#define LOADG(VB, WB, g)                                                      \
  do {                                                                        \
    _Pragma("unroll") for (int j_ = 0; j_ < 4; ++j_) {                        \
      int2 p_ = pr[(g) * 4 + j_];                                             \
      WB[j_] = __int_as_float(p_.y);                                          \
      VB[j_] = *(const gvec*)((const char*)hin + (unsigned)(p_.x + laneByte));\
    }                                                                         \
  } while (0)

#define FMAG(VB, WB)                                                          \
  do {                                                                        \
    _Pragma("unroll") for (int j_ = 0; j_ < 4; ++j_)                          \
        _Pragma("unroll") for (int k_ = 0; k_ < VEC; ++k_)                    \
            acc[k_] += WB[j_] * (float)VB[j_][k_];                            \
  } while (0)

  for (int base = 0; base < deg; base += 64) {
    int cn = min(64, deg - base);

    // ---- producer phase: this lane's edge -> (soff, w[h]) ----
    int soff = 0;
    float w_l[HH];
#pragma unroll
    for (int h = 0; h < HH; ++h) w_l[h] = 0.f;
    if (lane < cn) {
      int s = esrc[e0 + base + lane];
      soff = s * (CT * 2);
      if (HH == 4) {
        float4 sv = ((const float4*)sArr)[s];
        float svv[4] = {sv.x, sv.y, sv.z, sv.w};
#pragma unroll
        for (int h = 0; h < 4; ++h) {
          float e = svv[h] + dloc[h];
          e = (e > 0.f) ? e : 0.2f * e;
          w_l[h] = __expf(e - mn[h]);
        }
      } else {
        float e = sArr[s] + dloc[0];
        e = (e > 0.f) ? e : 0.2f * e;
        w_l[0] = __expf(e - mn[0]);
      }
    }
#pragma unroll
    for (int h = 0; h < HH; ++h) dsum[h] += w_l[h];

#pragma unroll
    for (int h = 0; h < HH; ++h)
      pw[h * 66 + lane] = make_int2(soff, __float_as_int(w_l[h]));
    // same-wave LDS visibility: drain DS queue; "memory" clobber orders the
    // surrounding ds_write/ds_read (no cross-wave sharing -> no s_barrier)
    asm volatile("s_waitcnt lgkmcnt(0)" ::: "memory");

    // ---- consumer phase: pipelined gather+FMA, groups of 4 edges ----
    int cng = (cn + 3) >> 2;  // tail edges padded with w=0 by producer
    gvec vA[4], vB[4];
    float wA[4], wB[4];
    LOADG(vA, wA, 0);
    int g = 0;
    while (g + 2 < cng) {
      LOADG(vB, wB, g + 1);
      FMAG(vA, wA);
      LOADG(vA, wA, g + 2);
      FMAG(vB, wB);
      g += 2;
    }
    if (g + 1 < cng) {
      LOADG(vB, wB, g + 1);
      FMAG(vA, wA);
      FMAG(vB, wB);
    } else {
      FMAG(vA, wA);
    }
  }
#undef LOADG
#undef FMAG

  // ---- denominator: one wave reduction per head, then per-lane select ----
  float dn;
  if (HH == 4) {
    float t0 = dsum[0], t1 = dsum[1], t2 = dsum[2], t3 = dsum[3];
#pragma unroll
    for (int m = 1; m < 64; m <<= 1) {
      t0 += __shfl_xor(t0, m);
      t1 += __shfl_xor(t1, m);
      t2 += __shfl_xor(t2, m);
      t3 += __shfl_xor(t3, m);
    }
    dn = (myhead < 2) ? (myhead == 0 ? t0 : t1) : (myhead == 2 ? t2 : t3);
  } else {
    float t0 = dsum[0];
#pragma unroll
    for (int m = 1; m < 64; m <<= 1) t0 += __shfl_xor(t0, m);
    dn = t0;
  }
  dn += 1e-16f;

  struct alignas(sizeof(OutT) * VEC) OutV { OutT v[VEC]; } ov;
#pragma unroll
  for (int k = 0; k < VEC; ++k) {
    float v = acc[k] / dn + bias[lane * VEC + k];
    if (DOELU) v = (v > 0.f) ? v : expm1f(v);
    ov.v[k] = (OutT)v;
  }
  *(OutV*)(outp + (size_t)n * CT + lane * VEC) = ov;
}

// ---------------------------------------------------------------------------
// Allocation head (Wh1 staged in LDS, persistent blocks)
// ---------------------------------------------------------------------------
__global__ __launch_bounds__(256) void k_head(
    const float* __restrict__ emb, const float* __restrict__ Wh1,
    const float* __restrict__ bh1, const float* __restrict__ Wh2,
    const float* __restrict__ bh2, float* __restrict__ scores, int N) {
  __shared__ float w1s[64 * 132];
  __shared__ float w2s[64];
  __shared__ float b1s[64];
  int t = threadIdx.x;
  for (int i = t; i < 64 * 32; i += 256) {
    int r = i >> 5, c4 = i & 31;
    float4 v = ((const float4*)Wh1)[i];
    *(float4*)&w1s[r * 132 + c4 * 4] = v;
  }
  if (t < 64) { w2s[t] = Wh2[t]; b1s[t] = bh1[t]; }
  __syncthreads();
  float b2v = bh2[0];
  int wave = t >> 6, lane = t & 63;
  int gw = blockIdx.x * 4 + wave;
  int nw = gridDim.x * 4;
  for (int n = gw; n < N; n += nw) {
    float2 xv = ((const float2*)(emb + (size_t)n * 128))[lane];
    float z = b1s[lane];
#pragma unroll
    for (int j = 0; j < 32; ++j) {
      float4 w = *(const float4*)&w1s[lane * 132 + 4 * j];
      float a0 = __shfl(xv.x, 2 * j);
      float a1 = __shfl(xv.y, 2 * j);
      float a2 = __shfl(xv.x, 2 * j + 1);
      float a3 = __shfl(xv.y, 2 * j + 1);
      z += w.x * a0 + w.y * a1 + w.z * a2 + w.w * a3;
    }
    z = fmaxf(z, 0.f);
    float v = z * w2s[lane];
#pragma unroll
    for (int off = 32; off; off >>= 1) v += __shfl_down(v, off);
    if (lane == 0) scores[n] = 1.f / (1.f + __expf(-(v + b2v)));
  }
}

// ---------------------------------------------------------------------------

extern "C" void kernel_launch(void* const* d_in, const int* in_sizes, int n_in,
                              void* d_out, int out_size, void* d_ws, size_t ws_size,
                              hipStream_t stream) {
  const float* x   = (const float*)d_in[0];
  const int*   ei  = (const int*)d_in[1];
  const float* W1  = (const float*)d_in[2];
  const float* as1 = (const float*)d_in[3];
  const float* ad1 = (const float*)d_in[4];
  const float* b1  = (const float*)d_in[5];
  const float* W2  = (const float*)d_in[6];
  const float* as2 = (const float*)d_in[7];
  const float* ad2 = (const float*)d_in[8];
  const float* b2  = (const float*)d_in[9];
  const float* W3  = (const float*)d_in[10];
  const float* as3 = (const float*)d_in[11];
  const float* ad3 = (const float*)d_in[12];
  const float* b3  = (const float*)d_in[13];
  const float* Wh1 = (const float*)d_in[14];
  const float* bh1 = (const float*)d_in[15];
  const float* Wh2 = (const float*)d_in[16];
  const float* bh2 = (const float*)d_in[17];
  float* out = (float*)d_out;

  const int F = 256, HC = 512, H = 4, C = 128;
  const int N = in_sizes[0] / F;
  const int E = in_sizes[1] / 2;
  const int Et = E + N;
  const int* srcArr = ei;
  const int* dstArr = ei + E;

  char* ws = (char*)d_ws;
  size_t off = 0;
  auto alloc = [&](size_t bytes) -> void* {
    void* p = ws + off;
    off += (bytes + 255) & ~(size_t)255;
    return p;
  };
  f16*   h16    = (f16*)alloc((size_t)N * HC * 2);
  f16*   hAgg   = (f16*)alloc((size_t)N * HC * 2);
  f16*   xh     = (f16*)alloc((size_t)N * F * 2);
  f16*   W1h    = (f16*)alloc((size_t)HC * F * 2);
  f16*   W2h    = (f16*)alloc((size_t)HC * HC * 2);
  f16*   W3h    = (f16*)alloc((size_t)C * HC * 2);
  int* row_ptr  = (int*)alloc((size_t)(N + 1) * 4);
  // zero region: cnt (N ints) + 3x4 gmax uints, one memset
  char* zr      = (char*)alloc((size_t)N * 4 + 64);
  int* cnt      = (int*)zr;
  unsigned* gm1 = (unsigned*)(zr + (size_t)N * 4);
  unsigned* gm2 = gm1 + 4;
  unsigned* gm3 = gm1 + 8;
  int* cursor   = (int*)alloc((size_t)N * 4);
  int* esrc     = (int*)alloc((size_t)Et * 4);
  float* sArr   = (float*)alloc((size_t)N * H * 4);
  float* dArr   = (float*)alloc((size_t)N * H * 4);
  int* bsum     = (int*)alloc((size_t)1028 * 4);
  (void)ws_size; (void)n_in; (void)out_size;

  // ---- CSR build ----
  hipMemsetAsync(zr, 0, (size_t)N * 4 + 64, stream);
  int eb = (Et + 255) / 256;
  int nb = (N + 1023) / 1024;
  k_count<<<eb, 256, 0, stream>>>(dstArr, cnt, E, Et);
  k_scanA<<<nb, 256, 0, stream>>>(cnt, row_ptr, bsum, N);
  k_scanB<<<1, 1024, 0, stream>>>(bsum, nb);
  k_scanC<<<(N + 256) / 256, 256, 0, stream>>>(row_ptr, cursor, bsum, N, nb);
  k_fill<<<eb, 256, 0, stream>>>(dstArr, srcArr, cursor, esrc, E, Et);

  // ---- fp16 conversions (one launch) ----
  int c0 = N * F / 4, c1 = HC * F / 4, c2 = HC * HC / 4, c3 = C * HC / 4;
  int ctot = c0 + c1 + c2 + c3;
  k_f2h4<<<(ctot + 255) / 256, 256, 0, stream>>>(x, xh, c0, W1, W1h, c1,
                                                 W2, W2h, c2, W3, W3h, c3);

  int aggGrid = (N + 3) / 4;
  int mblk = (N + 127) / 128;
  int nblk1 = 4 * mblk;   // layers 1,2: nbx=4
  int nblk3 = mblk;       // layer 3:    nbx=1

  // ---- layer 1: F -> H*C, elu ----
  k_hgemm_nt<<<nblk1, 256, 0, stream>>>(xh, W1h, h16, N, HC, F, 4,
                                        as1, ad1, sArr, dArr, gm1, H);
  k_aggregate<4, 512, true, f16><<<aggGrid, 256, 0, stream>>>(
      h16, sArr, dArr, row_ptr, esrc, gm1, b1, hAgg, N, E);

  // ---- layer 2: H*C -> H*C, elu ----
  k_hgemm_nt<<<nblk1, 256, 0, stream>>>(hAgg, W2h, h16, N, HC, HC, 4,
                                        as2, ad2, sArr, dArr, gm2, H);
  k_aggregate<4, 512, true, f16><<<aggGrid, 256, 0, stream>>>(
      h16, sArr, dArr, row_ptr, esrc, gm2, b2, hAgg, N, E);

  // ---- layer 3: H*C -> C, single head, no concat/elu -> embeddings ----
  k_hgemm_nt<<<nblk3, 256, 0, stream>>>(hAgg, W3h, h16, N, C, HC, 1,
                                        as3, ad3, sArr, dArr, gm3, 1);
  k_aggregate<1, 128, false, float><<<aggGrid, 256, 0, stream>>>(
      h16, sArr, dArr, row_ptr, esrc, gm3, b3, out, N, E);

  // ---- allocation head ----
  k_head<<<512, 256, 0, stream>>>(out, Wh1, bh1, Wh2, bh2, out + (size_t)N * C, N);
}

// Round 4
// 743.462 us; speedup vs baseline: 1.1385x; 1.0210x over previous
//
#include <hip/hip_runtime.h>
#include <math.h>

typedef _Float16 f16;
typedef f16 f16x2 __attribute__((ext_vector_type(2)));
typedef f16 f16x4 __attribute__((ext_vector_type(4)));
typedef f16 f16x8 __attribute__((ext_vector_type(8)));
typedef float f32x4 __attribute__((ext_vector_type(4)));

template <int V> struct VecT;
template <> struct VecT<2> { using T = f16 __attribute__((ext_vector_type(2))); };
template <> struct VecT<4> { using T = f16 __attribute__((ext_vector_type(4))); };
template <> struct VecT<8> { using T = f16 __attribute__((ext_vector_type(8))); };

__device__ __forceinline__ unsigned ordf(float f) {
  unsigned u = __float_as_uint(f);
  return (u >> 31) ? ~u : (u | 0x80000000u);
}
__device__ __forceinline__ float unordf(unsigned u) {
  return (u >> 31) ? __uint_as_float(u & 0x7fffffffu) : __uint_as_float(~u);
}

// ---------------------------------------------------------------------------
// CSR build: histogram of dst -> 3-stage parallel scan -> fill src-id array
// Edge id space: [0, E) = real edges, [E, E+N) = self loops (src=dst=id-E)
// ---------------------------------------------------------------------------

__global__ void k_count(const int* __restrict__ dstArr, int* __restrict__ cnt,
                        int E, int Et) {
  int i = blockIdx.x * blockDim.x + threadIdx.x;
  if (i >= Et) return;
  int d = (i < E) ? dstArr[i] : (i - E);
  atomicAdd(&cnt[d], 1);
}

__global__ __launch_bounds__(256) void k_scanA(const int* __restrict__ cnt,
                                               int* __restrict__ row_ptr,
                                               int* __restrict__ bsum, int n) {
  __shared__ int part[256];
  int t = threadIdx.x;
  int base = blockIdx.x * 1024 + t * 4;
  int4 v = make_int4(0, 0, 0, 0);
  if (base + 3 < n) v = *(const int4*)&cnt[base];
  else {
    if (base + 0 < n) v.x = cnt[base + 0];
    if (base + 1 < n) v.y = cnt[base + 1];
    if (base + 2 < n) v.z = cnt[base + 2];
    if (base + 3 < n) v.w = cnt[base + 3];
  }
  int s = v.x + v.y + v.z + v.w;
  part[t] = s;
  __syncthreads();
  for (int off = 1; off < 256; off <<= 1) {
    int x = (t >= off) ? part[t - off] : 0;
    __syncthreads();
    part[t] += x;
    __syncthreads();
  }
  int p0 = (t == 0) ? 0 : part[t - 1];
  int p1 = p0 + v.x, p2 = p1 + v.y, p3 = p2 + v.z;
  if (base + 0 < n) row_ptr[base + 0] = p0;
  if (base + 1 < n) row_ptr[base + 1] = p1;
  if (base + 2 < n) row_ptr[base + 2] = p2;
  if (base + 3 < n) row_ptr[base + 3] = p3;
  if (t == 255) bsum[blockIdx.x] = part[255];
}

__global__ __launch_bounds__(1024) void k_scanB(int* __restrict__ bsum, int nb) {
  __shared__ int part[1024];
  int t = threadIdx.x;
  int v = (t < nb) ? bsum[t] : 0;
  part[t] = v;
  __syncthreads();
  for (int off = 1; off < 1024; off <<= 1) {
    int x = (t >= off) ? part[t - off] : 0;
    __syncthreads();
    part[t] += x;
    __syncthreads();
  }
  if (t < nb) bsum[t] = (t == 0) ? 0 : part[t - 1];
  if (t == 1023) bsum[nb] = part[1023];
}

__global__ void k_scanC(int* __restrict__ row_ptr, int* __restrict__ cursor,
                        const int* __restrict__ bsum, int n, int nb) {
  int i = blockIdx.x * blockDim.x + threadIdx.x;
  if (i < n) {
    int v = row_ptr[i] + bsum[i >> 10];
    row_ptr[i] = v;
    cursor[i] = v;
  }
  if (i == n) row_ptr[n] = bsum[nb];
}

__global__ void k_fill(const int* __restrict__ dstArr,
                       const int* __restrict__ srcArr, int* __restrict__ cursor,
                       int* __restrict__ esrc, int E, int Et) {
  int i = blockIdx.x * blockDim.x + threadIdx.x;
  if (i >= Et) return;
  int d, s;
  if (i < E) { d = dstArr[i]; s = srcArr[i]; }
  else       { d = i - E; s = d; }
  int pos = atomicAdd(&cursor[d], 1);
  esrc[pos] = s;
}

// ---------------------------------------------------------------------------
// fp32 -> fp16 conversion, 4 segments in one launch (each n multiple of 4)
// ---------------------------------------------------------------------------
__global__ void k_f2h4(const float* s0, f16* d0, int n0,
                       const float* s1, f16* d1, int n1,
                       const float* s2, f16* d2, int n2,
                       const float* s3, f16* d3, int n3) {
  int i = blockIdx.x * blockDim.x + threadIdx.x;
  const float* s; f16* d;
  if (i < n0) { s = s0; d = d0; }
  else if ((i -= n0) < n1) { s = s1; d = d1; }
  else if ((i -= n1) < n2) { s = s2; d = d2; }
  else if ((i -= n2) < n3) { s = s3; d = d3; }
  else return;
  float4 v = ((const float4*)s)[i];
  union { f16 h[4]; double dd; } u;
  u.h[0] = (f16)v.x; u.h[1] = (f16)v.y; u.h[2] = (f16)v.z; u.h[3] = (f16)v.w;
  ((double*)d)[i] = u.dd;
}

// ---------------------------------------------------------------------------
// HGEMM (fp16 MFMA, fp32 accumulate): C[M,Nn] = A[M,K] @ B[Nn,K]^T
// 128x128 tile, BK=32, 256 thr = 4 waves, wave = 64x64 quadrant (4x4 MFMAs).
// v5: RING-3 LDS pipeline (48 KB, keeps 3 blocks/CU) with depth-2 prefetch:
// prologue stages tiles 0,1; steady iter t stages tile t+2 then waits
// vmcnt(8) (= 2 stages in flight, oldest landed) -> ~2 compute phases +
// inter-block TLP cover the ~900cy HBM latency instead of ~1 phase (v4 was
// depth-1: every iter stalled on the just-issued loads).
// Bijective XCD-chunk swizzle for A-panel L2 reuse. Fused GAT-attention
// epilogue; block-reduced gmax (one atomic per block).
// ---------------------------------------------------------------------------
__global__ __launch_bounds__(256) void k_hgemm_nt(
    const f16* __restrict__ A, const f16* __restrict__ B,
    f16* __restrict__ C, int M, int Nn, int K, int nbx,
    const float* __restrict__ a_src, const float* __restrict__ a_dst,
    float* __restrict__ sArr, float* __restrict__ dArr,
    unsigned* __restrict__ gmaxU, int H) {
  __shared__ f16 As[3 * 4096];
  __shared__ f16 Bs[3 * 4096];
  int tid = threadIdx.x;
  int wave = tid >> 6, lane = tid & 63;
  int quad = lane >> 4, l16 = lane & 15;

  // ---- XCD-chunk swizzle (bijective, m204 form) ----
  int nwg = gridDim.x;
  int orig = blockIdx.x;
  int q = nwg >> 3, r = nwg & 7;
  int xcd = orig & 7, pos = orig >> 3;
  int swz = (xcd < r) ? (xcd * (q + 1) + pos)
                      : (r * (q + 1) + (xcd - r) * q + pos);
  int bx = swz % nbx;
  int by = swz / nbx;
  int m0 = by * 128, n0 = bx * 128;
  int wm = (wave & 1) * 64, wn = (wave >> 1) * 64;

  // ---- staging addresses (wave w stages rows w*16.. and 64+w*16.. of A and B)
  int lr = lane >> 2;            // row within 16-row group
  int lc = lane & 3;             // lds chunk slot this lane fills
  int chunk = lc ^ ((lr >> 1) & 3);  // global chunk to fetch (swizzle)
  int rb0 = wave * 16;
  int rb1 = 64 + wave * 16;
  int ga0 = m0 + rb0 + lr; if (ga0 >= M) ga0 = M - 1;
  int ga1 = m0 + rb1 + lr; if (ga1 >= M) ga1 = M - 1;
  const f16* gA0 = A + (size_t)ga0 * K + chunk * 8;
  const f16* gA1 = A + (size_t)ga1 * K + chunk * 8;
  const f16* gB0 = B + (size_t)(n0 + rb0 + lr) * K + chunk * 8;
  const f16* gB1 = B + (size_t)(n0 + rb1 + lr) * K + chunk * 8;

  // ---- fragment read pointers (chunk = quad ^ ((l16>>1)&3))
  int rsw = (quad ^ ((l16 >> 1) & 3)) * 8;
  const f16* Ard[4];
  const f16* Brd[4];
#pragma unroll
  for (int i = 0; i < 4; ++i) {
    Ard[i] = &As[(wm + i * 16 + l16) * 32 + rsw];
    Brd[i] = &Bs[(wn + i * 16 + l16) * 32 + rsw];
  }

  f32x4 acc[4][4];
#pragma unroll
  for (int i = 0; i < 4; ++i)
#pragma unroll
    for (int j = 0; j < 4; ++j) acc[i][j] = (f32x4)(0.f);

#define GLDS(gp, lp)                                                     \
  __builtin_amdgcn_global_load_lds(                                      \
      (const __attribute__((address_space(1))) void*)(gp),               \
      (__attribute__((address_space(3))) void*)(lp), 16, 0, 0)
#define STAGE(buf, kk)                                                   \
  do {                                                                   \
    GLDS(gA0 + (kk), As + (buf) * 4096 + rb0 * 32);                      \
    GLDS(gA1 + (kk), As + (buf) * 4096 + rb1 * 32);                      \
    GLDS(gB0 + (kk), Bs + (buf) * 4096 + rb0 * 32);                      \
    GLDS(gB1 + (kk), Bs + (buf) * 4096 + rb1 * 32);                      \
  } while (0)
#define COMPUTE(bufidx)                                                       \
  do {                                                                        \
    f16x8 af[4], bf[4];                                                       \
    _Pragma("unroll") for (int i_ = 0; i_ < 4; ++i_)                          \
        af[i_] = *(const f16x8*)(Ard[i_] + (bufidx) * 4096);                  \
    _Pragma("unroll") for (int j_ = 0; j_ < 4; ++j_)                          \
        bf[j_] = *(const f16x8*)(Brd[j_] + (bufidx) * 4096);                  \
    _Pragma("unroll") for (int i_ = 0; i_ < 4; ++i_)                          \
        _Pragma("unroll") for (int j_ = 0; j_ < 4; ++j_)                      \
            acc[i_][j_] = __builtin_amdgcn_mfma_f32_16x16x32_f16(             \
                af[i_], bf[j_], acc[i_][j_], 0, 0, 0);                        \
  } while (0)

  int nt = K >> 5;  // 8 or 16, always >= 3
  STAGE(0, 0);
  STAGE(1, 32);
  int cur = 0, sb = 2;
  for (int t = 0; t + 2 < nt; ++t) {
    STAGE(sb, (t + 2) << 5);
    // 12 loads outstanding; wait to 8 -> tile t's 4 landed (this wave).
    // STAGE above overwrites buf read at iter t-1; t-1's trailing barrier
    // guarantees those reads completed.
    asm volatile("s_waitcnt vmcnt(8)\n\ts_barrier" ::: "memory");
    COMPUTE(cur);
    asm volatile("s_barrier" ::: "memory");
    cur = (cur == 2) ? 0 : cur + 1;
    sb = (sb == 2) ? 0 : sb + 1;
  }
  // epilogue peel: drain 8 -> 4 -> 0
  asm volatile("s_waitcnt vmcnt(4)\n\ts_barrier" ::: "memory");
  COMPUTE(cur);
  asm volatile("s_barrier" ::: "memory");
  cur = (cur == 2) ? 0 : cur + 1;
  asm volatile("s_waitcnt vmcnt(0)\n\ts_barrier" ::: "memory");
  COMPUTE(cur);
#undef STAGE
#undef GLDS
#undef COMPUTE

  // ---- C store ----
#pragma unroll
  for (int i = 0; i < 4; ++i) {
#pragma unroll
    for (int r = 0; r < 4; ++r) {
      int m = m0 + wm + i * 16 + quad * 4 + r;
      if (m < M) {
        f16* Cp = C + (size_t)m * Nn + n0 + wn + l16;
#pragma unroll
        for (int j = 0; j < 4; ++j) Cp[j * 16] = (f16)acc[i][j][r];
      }
    }
  }

  // ---- fused attention scalars ----
  float av[4], ad[4];
#pragma unroll
  for (int j = 0; j < 4; ++j) {
    int col = n0 + wn + l16 + j * 16;
    av[j] = a_src[col];
    ad[j] = a_dst[col];
  }
  float sp[16], dp[16];
#pragma unroll
  for (int i = 0; i < 4; ++i)
#pragma unroll
    for (int r = 0; r < 4; ++r) {
      float ss = 0.f, dd = 0.f;
#pragma unroll
      for (int j = 0; j < 4; ++j) {
        ss += acc[i][j][r] * av[j];
        dd += acc[i][j][r] * ad[j];
      }
#pragma unroll
      for (int msk = 1; msk < 16; msk <<= 1) {
        ss += __shfl_xor(ss, msk);
        dd += __shfl_xor(dd, msk);
      }
      sp[i * 4 + r] = ss;
      dp[i * 4 + r] = dd;
    }

  __syncthreads();  // done reading As/Bs; reuse as float scratch
  float* fb = (float*)As;
  int wv = wn >> 6;
  if (l16 == 0) {
#pragma unroll
    for (int i = 0; i < 4; ++i)
#pragma unroll
      for (int r = 0; r < 4; ++r) {
        int row = wm + i * 16 + quad * 4 + r;
        fb[wv * 128 + row] = sp[i * 4 + r];
        fb[256 + wv * 128 + row] = dp[i * 4 + r];
      }
  }
  __syncthreads();
  float sval = -3.0e38f;
  if (tid < 128) {
    int m = m0 + tid;
    if (m < M) {
      float s = fb[tid] + fb[128 + tid];
      float d = fb[256 + tid] + fb[384 + tid];
      int head = n0 >> 7;
      sArr[(size_t)m * H + head] = s;
      dArr[(size_t)m * H + head] = d;
      sval = s;
    }
  }
  // block max -> single atomic (waves 2,3 contribute -inf)
  float mx = sval;
#pragma unroll
  for (int msk = 32; msk; msk >>= 1) mx = fmaxf(mx, __shfl_xor(mx, msk));
  __syncthreads();
  if (lane == 0) fb[512 + wave] = mx;
  __syncthreads();
  if (tid == 0) {
    float m01 = fmaxf(fb[512], fb[513]);
    atomicMax(&gmaxU[n0 >> 7], ordf(m01));
  }
}

// ---------------------------------------------------------------------------
// Segment softmax + aggregation: ONE WAVE PER NODE, no barriers.
// esrc holds resolved src ids; per-chunk (soff, w) pairs staged head-major
// in LDS, stride 66 (conflict-free). Inner loop: 1 ds_read_b64 per edge +
// pipelined 16B gathers, groups of edges, double-buffered registers.
// v5: HH==1 (layer 3, 128-dim rows) processes TWO edges per wave per load
// slot: lanes 0-31 take edge 2g+j*2, lanes 32-63 edge 2g+j*2+1, 8 B/lane.
// The layer-3 aggregate is edge-rate-bound (256 B rows), so doubling
// edges/iter ~halves it. Cross-half combine via one shfl_xor(32) pass.
// Shift = leaky(gmax + d_n) >= segment max (leaky monotone; softmax
// shift-invariant). gmax passed as order-preserving uint.
// ---------------------------------------------------------------------------
template <int HH, int CT, bool DOELU, typename OutT>
__global__ __launch_bounds__(256) void k_aggregate(
    const f16* __restrict__ hin, const float* __restrict__ sArr,
    const float* __restrict__ dArr, const int* __restrict__ row_ptr,
    const int* __restrict__ esrc, const unsigned* __restrict__ gmaxU,
    const float* __restrict__ bias, OutT* __restrict__ outp, int N, int E) {
  constexpr int VEC = (HH == 1) ? 4 : (CT / 64);
  constexpr int CPER = CT / HH;
  using gvec = typename VecT<VEC>::T;

  __shared__ int2 pairs[4][HH * 66];  // [wave][h*66 + edge] = {soff, w_h}

  int wave = threadIdx.x >> 6;
  int lane = threadIdx.x & 63;
  int n = blockIdx.x * 4 + wave;
  if (n >= N) return;
  int e0 = row_ptr[n];
  int deg = row_ptr[n + 1] - e0;

  const int myhead = (HH == 1) ? 0 : (lane * VEC) / CPER;
  const int l32 = lane & 31, half = lane >> 5;
  const int laneByte = (HH == 1) ? l32 * 8 : lane * VEC * 2;

  float dloc[HH], mn[HH];
#pragma unroll
  for (int h = 0; h < HH; ++h) {
    dloc[h] = dArr[n * HH + h];
    float m = unordf(gmaxU[h]) + dloc[h];
    mn[h] = (m > 0.f) ? m : 0.2f * m;
  }

  float acc[VEC];
#pragma unroll
  for (int k = 0; k < VEC; ++k) acc[k] = 0.f;
  float dsum[HH];
#pragma unroll
  for (int h = 0; h < HH; ++h) dsum[h] = 0.f;

  int2* pw = &pairs[wave][0];
  const int2* pr = &pairs[wave][myhead * 66];

// HH==4: pair idx g*4+j (one edge per slot). HH==1: pair idx g*8+j*2+half
// (two edges per slot, split across wave halves).
#define PIDX(g, j) ((HH == 1) ? ((g) * 8 + (j) * 2 + half) : ((g) * 4 + (j)))
#define LOADG(VB, WB, g)                                                      \
  do {                                                                        \
    _Pragma("unroll") for (int j_ = 0; j_ < 4; ++j_) {                        \
      int2 p_ = pr[PIDX(g, j_)];                                              \
      WB[j_] = __int_as_float(p_.y);                                          \
      VB[j_] = *(const gvec*)((const char*)hin + (unsigned)(p_.x + laneByte));\
    }                                                                         \
  } while (0)

#define FMAG(VB, WB)                                                          \
  do {                                                                        \
    _Pragma("unroll") for (int j_ = 0; j_ < 4; ++j_)                          \
        _Pragma("unroll") for (int k_ = 0; k_ < VEC; ++k_)                    \
            acc[k_] += WB[j_] * (float)VB[j_][k_];                            \
  } while (0)

  for (int base = 0; base < deg; base += 64) {
    int cn = min(64, deg - base);

    // ---- producer phase: this lane's edge -> (soff, w[h]) ----
    int soff = 0;
    float w_l[HH];
#pragma unroll
    for (int h = 0; h < HH; ++h) w_l[h] = 0.f;
    if (lane < cn) {
      int s = esrc[e0 + base + lane];
      soff = s * (CT * 2);
      if (HH == 4) {
        float4 sv = ((const float4*)sArr)[s];
        float svv[4] = {sv.x, sv.y, sv.z, sv.w};
#pragma unroll
        for (int h = 0; h < 4; ++h) {
          float e = svv[h] + dloc[h];
          e = (e > 0.f) ? e : 0.2f * e;
          w_l[h] = __expf(e - mn[h]);
        }
      } else {
        float e = sArr[s] + dloc[0];
        e = (e > 0.f) ? e : 0.2f * e;
        w_l[0] = __expf(e - mn[0]);
      }
    }
#pragma unroll
    for (int h = 0; h < HH; ++h) dsum[h] += w_l[h];

#pragma unroll
    for (int h = 0; h < HH; ++h)
      pw[h * 66 + lane] = make_int2(soff, __float_as_int(w_l[h]));
    // same-wave LDS visibility: drain DS queue; "memory" clobber orders the
    // surrounding ds_write/ds_read (no cross-wave sharing -> no s_barrier)
    asm volatile("s_waitcnt lgkmcnt(0)" ::: "memory");

    // ---- consumer phase: pipelined gather+FMA ----
    // edges per group: HH==4 -> 4, HH==1 -> 8 (padded slots have w=0)
    int cng = (HH == 1) ? ((cn + 7) >> 3) : ((cn + 3) >> 2);
    gvec vA[4], vB[4];
    float wA[4], wB[4];
    LOADG(vA, wA, 0);
    int g = 0;
    while (g + 2 < cng) {
      LOADG(vB, wB, g + 1);
      FMAG(vA, wA);
      LOADG(vA, wA, g + 2);
      FMAG(vB, wB);
      g += 2;
    }
    if (g + 1 < cng) {
      LOADG(vB, wB, g + 1);
      FMAG(vA, wA);
      FMAG(vB, wB);
    } else {
      FMAG(vA, wA);
    }
  }
#undef LOADG
#undef FMAG
#undef PIDX

  // ---- HH==1: combine the two half-wave edge partitions ----
  if (HH == 1) {
#pragma unroll
    for (int k = 0; k < VEC; ++k) acc[k] += __shfl_xor(acc[k], 32);
  }

  // ---- denominator: one wave reduction per head, then per-lane select ----
  float dn;
  if (HH == 4) {
    float t0 = dsum[0], t1 = dsum[1], t2 = dsum[2], t3 = dsum[3];
#pragma unroll
    for (int m = 1; m < 64; m <<= 1) {
      t0 += __shfl_xor(t0, m);
      t1 += __shfl_xor(t1, m);
      t2 += __shfl_xor(t2, m);
      t3 += __shfl_xor(t3, m);
    }
    dn = (myhead < 2) ? (myhead == 0 ? t0 : t1) : (myhead == 2 ? t2 : t3);
  } else {
    float t0 = dsum[0];
#pragma unroll
    for (int m = 1; m < 64; m <<= 1) t0 += __shfl_xor(t0, m);
    dn = t0;
  }
  dn += 1e-16f;

  if (HH == 1) {
    if (lane < 32) {
      struct alignas(16) OutV { OutT v[4]; } ov;
#pragma unroll
      for (int k = 0; k < 4; ++k) {
        float v = acc[k] / dn + bias[l32 * 4 + k];
        if (DOELU) v = (v > 0.f) ? v : expm1f(v);
        ov.v[k] = (OutT)v;
      }
      *(OutV*)(outp + (size_t)n * CT + l32 * 4) = ov;
    }
  } else {
    struct alignas(sizeof(OutT) * VEC) OutV { OutT v[VEC]; } ov;
#pragma unroll
    for (int k = 0; k < VEC; ++k) {
      float v = acc[k] / dn + bias[lane * VEC + k];
      if (DOELU) v = (v > 0.f) ? v : expm1f(v);
      ov.v[k] = (OutT)v;
    }
    *(OutV*)(outp + (size_t)n * CT + lane * VEC) = ov;
  }
}

// ---------------------------------------------------------------------------
// Allocation head (Wh1 staged in LDS, persistent blocks)
// ---------------------------------------------------------------------------
__global__ __launch_bounds__(256) void k_head(
    const float* __restrict__ emb, const float* __restrict__ Wh1,
    const float* __restrict__ bh1, const float* __restrict__ Wh2,
    const float* __restrict__ bh2, float* __restrict__ scores, int N) {
  __shared__ float w1s[64 * 132];
  __shared__ float w2s[64];
  __shared__ float b1s[64];
  int t = threadIdx.x;
  for (int i = t; i < 64 * 32; i += 256) {
    int r = i >> 5, c4 = i & 31;
    float4 v = ((const float4*)Wh1)[i];
    *(float4*)&w1s[r * 132 + c4 * 4] = v;
  }
  if (t < 64) { w2s[t] = Wh2[t]; b1s[t] = bh1[t]; }
  __syncthreads();
  float b2v = bh2[0];
  int wave = t >> 6, lane = t & 63;
  int gw = blockIdx.x * 4 + wave;
  int nw = gridDim.x * 4;
  for (int n = gw; n < N; n += nw) {
    float2 xv = ((const float2*)(emb + (size_t)n * 128))[lane];
    float z = b1s[lane];
#pragma unroll
    for (int j = 0; j < 32; ++j) {
      float4 w = *(const float4*)&w1s[lane * 132 + 4 * j];
      float a0 = __shfl(xv.x, 2 * j);
      float a1 = __shfl(xv.y, 2 * j);
      float a2 = __shfl(xv.x, 2 * j + 1);
      float a3 = __shfl(xv.y, 2 * j + 1);
      z += w.x * a0 + w.y * a1 + w.z * a2 + w.w * a3;
    }
    z = fmaxf(z, 0.f);
    float v = z * w2s[lane];
#pragma unroll
    for (int off = 32; off; off >>= 1) v += __shfl_down(v, off);
    if (lane == 0) scores[n] = 1.f / (1.f + __expf(-(v + b2v)));
  }
}

// ---------------------------------------------------------------------------

extern "C" void kernel_launch(void* const* d_in, const int* in_sizes, int n_in,
                              void* d_out, int out_size, void* d_ws, size_t ws_size,
                              hipStream_t stream) {
  const float* x   = (const float*)d_in[0];
  const int*   ei  = (const int*)d_in[1];
  const float* W1  = (const float*)d_in[2];
  const float* as1 = (const float*)d_in[3];
  const float* ad1 = (const float*)d_in[4];
  const float* b1  = (const float*)d_in[5];
  const float* W2  = (const float*)d_in[6];
  const float* as2 = (const float*)d_in[7];
  const float* ad2 = (const float*)d_in[8];
  const float* b2  = (const float*)d_in[9];
  const float* W3  = (const float*)d_in[10];
  const float* as3 = (const float*)d_in[11];
  const float* ad3 = (const float*)d_in[12];
  const float* b3  = (const float*)d_in[13];
  const float* Wh1 = (const float*)d_in[14];
  const float* bh1 = (const float*)d_in[15];
  const float* Wh2 = (const float*)d_in[16];
  const float* bh2 = (const float*)d_in[17];
  float* out = (float*)d_out;

  const int F = 256, HC = 512, H = 4, C = 128;
  const int N = in_sizes[0] / F;
  const int E = in_sizes[1] / 2;
  const int Et = E + N;
  const int* srcArr = ei;
  const int* dstArr = ei + E;

  char* ws = (char*)d_ws;
  size_t off = 0;
  auto alloc = [&](size_t bytes) -> void* {
    void* p = ws + off;
    off += (bytes + 255) & ~(size_t)255;
    return p;
  };
  f16*   h16    = (f16*)alloc((size_t)N * HC * 2);
  f16*   hAgg   = (f16*)alloc((size_t)N * HC * 2);
  f16*   xh     = (f16*)alloc((size_t)N * F * 2);
  f16*   W1h    = (f16*)alloc((size_t)HC * F * 2);
  f16*   W2h    = (f16*)alloc((size_t)HC * HC * 2);
  f16*   W3h    = (f16*)alloc((size_t)C * HC * 2);
  int* row_ptr  = (int*)alloc((size_t)(N + 1) * 4);
  // zero region: cnt (N ints) + 3x4 gmax uints, one memset
  char* zr      = (char*)alloc((size_t)N * 4 + 64);
  int* cnt      = (int*)zr;
  unsigned* gm1 = (unsigned*)(zr + (size_t)N * 4);
  unsigned* gm2 = gm1 + 4;
  unsigned* gm3 = gm1 + 8;
  int* cursor   = (int*)alloc((size_t)N * 4);
  int* esrc     = (int*)alloc((size_t)Et * 4);
  float* sArr   = (float*)alloc((size_t)N * H * 4);
  float* dArr   = (float*)alloc((size_t)N * H * 4);
  int* bsum     = (int*)alloc((size_t)1028 * 4);
  (void)ws_size; (void)n_in; (void)out_size;

  // ---- CSR build ----
  hipMemsetAsync(zr, 0, (size_t)N * 4 + 64, stream);
  int eb = (Et + 255) / 256;
  int nb = (N + 1023) / 1024;
  k_count<<<eb, 256, 0, stream>>>(dstArr, cnt, E, Et);
  k_scanA<<<nb, 256, 0, stream>>>(cnt, row_ptr, bsum, N);
  k_scanB<<<1, 1024, 0, stream>>>(bsum, nb);
  k_scanC<<<(N + 256) / 256, 256, 0, stream>>>(row_ptr, cursor, bsum, N, nb);
  k_fill<<<eb, 256, 0, stream>>>(dstArr, srcArr, cursor, esrc, E, Et);

  // ---- fp16 conversions (one launch) ----
  int c0 = N * F / 4, c1 = HC * F / 4, c2 = HC * HC / 4, c3 = C * HC / 4;
  int ctot = c0 + c1 + c2 + c3;
  k_f2h4<<<(ctot + 255) / 256, 256, 0, stream>>>(x, xh, c0, W1, W1h, c1,
                                                 W2, W2h, c2, W3, W3h, c3);

  int aggGrid = (N + 3) / 4;
  int mblk = (N + 127) / 128;
  int nblk1 = 4 * mblk;   // layers 1,2: nbx=4
  int nblk3 = mblk;       // layer 3:    nbx=1

  // ---- layer 1: F -> H*C, elu ----
  k_hgemm_nt<<<nblk1, 256, 0, stream>>>(xh, W1h, h16, N, HC, F, 4,
                                        as1, ad1, sArr, dArr, gm1, H);
  k_aggregate<4, 512, true, f16><<<aggGrid, 256, 0, stream>>>(
      h16, sArr, dArr, row_ptr, esrc, gm1, b1, hAgg, N, E);

  // ---- layer 2: H*C -> H*C, elu ----
  k_hgemm_nt<<<nblk1, 256, 0, stream>>>(hAgg, W2h, h16, N, HC, HC, 4,
                                        as2, ad2, sArr, dArr, gm2, H);
  k_aggregate<4, 512, true, f16><<<aggGrid, 256, 0, stream>>>(
      h16, sArr, dArr, row_ptr, esrc, gm2, b2, hAgg, N, E);

  // ---- layer 3: H*C -> C, single head, no concat/elu -> embeddings ----
  k_hgemm_nt<<<nblk3, 256, 0, stream>>>(hAgg, W3h, h16, N, C, HC, 1,
                                        as3, ad3, sArr, dArr, gm3, 1);
  k_aggregate<1, 128, false, float><<<aggGrid, 256, 0, stream>>>(
      h16, sArr, dArr, row_ptr, esrc, gm3, b3, out, N, E);

  // ---- allocation head ----
  k_head<<<512, 256, 0, stream>>>(out, Wh1, bh1, Wh2, bh2, out + (size_t)N * C, N);
}

// Round 5
// 726.304 us; speedup vs baseline: 1.1654x; 1.0236x over previous
//
#include <hip/hip_runtime.h>
#include <math.h>

typedef _Float16 f16;
typedef f16 f16x2 __attribute__((ext_vector_type(2)));
typedef f16 f16x4 __attribute__((ext_vector_type(4)));
typedef f16 f16x8 __attribute__((ext_vector_type(8)));
typedef float f32x4 __attribute__((ext_vector_type(4)));

template <int V> struct VecT;
template <> struct VecT<2> { using T = f16 __attribute__((ext_vector_type(2))); };
template <> struct VecT<4> { using T = f16 __attribute__((ext_vector_type(4))); };
template <> struct VecT<8> { using T = f16 __attribute__((ext_vector_type(8))); };

__device__ __forceinline__ unsigned ordf(float f) {
  unsigned u = __float_as_uint(f);
  return (u >> 31) ? ~u : (u | 0x80000000u);
}
__device__ __forceinline__ float unordf(unsigned u) {
  return (u >> 31) ? __uint_as_float(u & 0x7fffffffu) : __uint_as_float(~u);
}

// ---------------------------------------------------------------------------
// CSR build: histogram of dst -> 3-stage parallel scan -> fill src-id array
// Edge id space: [0, E) = real edges, [E, E+N) = self loops (src=dst=id-E)
// ---------------------------------------------------------------------------

__global__ void k_count(const int* __restrict__ dstArr, int* __restrict__ cnt,
                        int E, int Et) {
  int i = blockIdx.x * blockDim.x + threadIdx.x;
  if (i >= Et) return;
  int d = (i < E) ? dstArr[i] : (i - E);
  atomicAdd(&cnt[d], 1);
}

__global__ __launch_bounds__(256) void k_scanA(const int* __restrict__ cnt,
                                               int* __restrict__ row_ptr,
                                               int* __restrict__ bsum, int n) {
  __shared__ int part[256];
  int t = threadIdx.x;
  int base = blockIdx.x * 1024 + t * 4;
  int4 v = make_int4(0, 0, 0, 0);
  if (base + 3 < n) v = *(const int4*)&cnt[base];
  else {
    if (base + 0 < n) v.x = cnt[base + 0];
    if (base + 1 < n) v.y = cnt[base + 1];
    if (base + 2 < n) v.z = cnt[base + 2];
    if (base + 3 < n) v.w = cnt[base + 3];
  }
  int s = v.x + v.y + v.z + v.w;
  part[t] = s;
  __syncthreads();
  for (int off = 1; off < 256; off <<= 1) {
    int x = (t >= off) ? part[t - off] : 0;
    __syncthreads();
    part[t] += x;
    __syncthreads();
  }
  int p0 = (t == 0) ? 0 : part[t - 1];
  int p1 = p0 + v.x, p2 = p1 + v.y, p3 = p2 + v.z;
  if (base + 0 < n) row_ptr[base + 0] = p0;
  if (base + 1 < n) row_ptr[base + 1] = p1;
  if (base + 2 < n) row_ptr[base + 2] = p2;
  if (base + 3 < n) row_ptr[base + 3] = p3;
  if (t == 255) bsum[blockIdx.x] = part[255];
}

__global__ __launch_bounds__(1024) void k_scanB(int* __restrict__ bsum, int nb) {
  __shared__ int part[1024];
  int t = threadIdx.x;
  int v = (t < nb) ? bsum[t] : 0;
  part[t] = v;
  __syncthreads();
  for (int off = 1; off < 1024; off <<= 1) {
    int x = (t >= off) ? part[t - off] : 0;
    __syncthreads();
    part[t] += x;
    __syncthreads();
  }
  if (t < nb) bsum[t] = (t == 0) ? 0 : part[t - 1];
  if (t == 1023) bsum[nb] = part[1023];
}

__global__ void k_scanC(int* __restrict__ row_ptr, int* __restrict__ cursor,
                        const int* __restrict__ bsum, int n, int nb) {
  int i = blockIdx.x * blockDim.x + threadIdx.x;
  if (i < n) {
    int v = row_ptr[i] + bsum[i >> 10];
    row_ptr[i] = v;
    cursor[i] = v;
  }
  if (i == n) row_ptr[n] = bsum[nb];
}

__global__ void k_fill(const int* __restrict__ dstArr,
                       const int* __restrict__ srcArr, int* __restrict__ cursor,
                       int* __restrict__ esrc, int E, int Et) {
  int i = blockIdx.x * blockDim.x + threadIdx.x;
  if (i >= Et) return;
  int d, s;
  if (i < E) { d = dstArr[i]; s = srcArr[i]; }
  else       { d = i - E; s = d; }
  int pos = atomicAdd(&cursor[d], 1);
  esrc[pos] = s;
}

// ---------------------------------------------------------------------------
// fp32 -> fp16 conversion, 4 segments in one launch (each n multiple of 4)
// ---------------------------------------------------------------------------
__global__ void k_f2h4(const float* s0, f16* d0, int n0,
                       const float* s1, f16* d1, int n1,
                       const float* s2, f16* d2, int n2,
                       const float* s3, f16* d3, int n3) {
  int i = blockIdx.x * blockDim.x + threadIdx.x;
  const float* s; f16* d;
  if (i < n0) { s = s0; d = d0; }
  else if ((i -= n0) < n1) { s = s1; d = d1; }
  else if ((i -= n1) < n2) { s = s2; d = d2; }
  else if ((i -= n2) < n3) { s = s3; d = d3; }
  else return;
  float4 v = ((const float4*)s)[i];
  union { f16 h[4]; double dd; } u;
  u.h[0] = (f16)v.x; u.h[1] = (f16)v.y; u.h[2] = (f16)v.z; u.h[3] = (f16)v.w;
  ((double*)d)[i] = u.dd;
}

// ---------------------------------------------------------------------------
// Layer-1 commuted attention: ws/wd precompute.
// ws_h = sum_c a_src[h,c] * W1[h*128+c, :]  (8 vectors of 256 fp32)
// rows 0-3 = src heads, 4-7 = dst heads.
// ---------------------------------------------------------------------------
__global__ __launch_bounds__(256) void k_ws(const float* __restrict__ W1,
                                            const float* __restrict__ as,
                                            const float* __restrict__ ad,
                                            float* __restrict__ wsb) {
  int b = blockIdx.x;          // 0..7
  int which = b >> 2, h = b & 3;
  int f = threadIdx.x;         // 0..255
  const float* av = (which ? ad : as) + h * 128;
  float acc = 0.f;
  for (int c = 0; c < 128; ++c)
    acc += av[c] * W1[(size_t)(h * 128 + c) * 256 + f];
  wsb[(which * 4 + h) * 256 + f] = acc;
}

// ---------------------------------------------------------------------------
// Layer-1 commuted attention: per-node s/d GEMV  (s_n[h] = x[n]·ws_h).
// One wave per node (grid-stride). ws held in 32 VGPRs per lane.
// Reduction: 3 butterfly steps within 8-lane groups (all 8 q), cndmask
// select p[lane&7], 3 butterfly steps across groups -> lane q holds total[q].
// Block-reduced gmax, 4 atomics per block.
// ---------------------------------------------------------------------------
__global__ __launch_bounds__(256) void k_sd(
    const f16* __restrict__ xh, const float* __restrict__ wsb,
    float* __restrict__ sArr, float* __restrict__ dArr,
    unsigned* __restrict__ gmaxU, int N) {
  __shared__ float mred[4][8];
  int tid = threadIdx.x;
  int wave = tid >> 6, lane = tid & 63;
  float wreg[8][4];
#pragma unroll
  for (int q = 0; q < 8; ++q) {
    float4 w = *(const float4*)&wsb[q * 256 + lane * 4];
    wreg[q][0] = w.x; wreg[q][1] = w.y; wreg[q][2] = w.z; wreg[q][3] = w.w;
  }
  int qsel = lane & 7;
  float rmax = -3.0e38f;  // lanes 0-3 track running max of s_head
  int step = gridDim.x * 4;
  for (int n = blockIdx.x * 4 + wave; n < N; n += step) {
    f16x4 xr = *(const f16x4*)(xh + (size_t)n * 256 + lane * 4);
    float xv[4];
#pragma unroll
    for (int k = 0; k < 4; ++k) xv[k] = (float)xr[k];
    float p[8];
#pragma unroll
    for (int q = 0; q < 8; ++q)
      p[q] = xv[0] * wreg[q][0] + xv[1] * wreg[q][1] +
             xv[2] * wreg[q][2] + xv[3] * wreg[q][3];
#pragma unroll
    for (int m = 1; m < 8; m <<= 1)
#pragma unroll
      for (int q = 0; q < 8; ++q) p[q] += __shfl_xor(p[q], m);
    float s01 = (qsel & 1) ? p[1] : p[0], s23 = (qsel & 1) ? p[3] : p[2];
    float s45 = (qsel & 1) ? p[5] : p[4], s67 = (qsel & 1) ? p[7] : p[6];
    float t0 = (qsel & 2) ? s23 : s01, t1 = (qsel & 2) ? s67 : s45;
    float v = (qsel & 4) ? t1 : t0;
    v += __shfl_xor(v, 8);
    v += __shfl_xor(v, 16);
    v += __shfl_xor(v, 32);
    if (lane < 4) {
      sArr[(size_t)n * 4 + lane] = v;
      rmax = fmaxf(rmax, v);
    } else if (lane < 8) {
      dArr[(size_t)n * 4 + (lane - 4)] = v;
    }
  }
  if (lane < 4) mred[wave][lane] = rmax;
  __syncthreads();
  if (tid < 4) {
    float m = fmaxf(fmaxf(mred[0][tid], mred[1][tid]),
                    fmaxf(mred[2][tid], mred[3][tid]));
    atomicMax(&gmaxU[tid], ordf(m));
  }
}

// ---------------------------------------------------------------------------
// Layer-1 commuted aggregation: gathers 512 B x-rows (HALF the bytes of
// h-rows) and accumulates 4 per-head weighted sums of the same row.
// out[n][h][:] = sum_e alpha_e^h x[src_e] / denom_h   -> [N,4,256] f16.
// Producer stages {soff, w0..w3} per edge in LDS (broadcast reads, free);
// consumer runs the pipelined gather+FMA, groups of 4 edges, dbuf regs.
// ---------------------------------------------------------------------------
__global__ __launch_bounds__(256) void k_aggx(
    const f16* __restrict__ xh, const float* __restrict__ sArr,
    const float* __restrict__ dArr, const int* __restrict__ row_ptr,
    const int* __restrict__ esrc, const unsigned* __restrict__ gmaxU,
    f16* __restrict__ outp, int N, int E) {
  __shared__ int soffA[4][72];
  __shared__ float4 w4A[4][64];
  int wave = threadIdx.x >> 6;
  int lane = threadIdx.x & 63;
  int n = blockIdx.x * 4 + wave;
  if (n >= N) return;
  int e0 = row_ptr[n];
  int deg = row_ptr[n + 1] - e0;

  float4 dl4 = ((const float4*)dArr)[n];
  float dloc[4] = {dl4.x, dl4.y, dl4.z, dl4.w};
  float mn[4];
#pragma unroll
  for (int h = 0; h < 4; ++h) {
    float m = unordf(gmaxU[h]) + dloc[h];
    mn[h] = (m > 0.f) ? m : 0.2f * m;
  }

  float acc[4][4];
#pragma unroll
  for (int h = 0; h < 4; ++h)
#pragma unroll
    for (int k = 0; k < 4; ++k) acc[h][k] = 0.f;
  float dsum[4] = {0.f, 0.f, 0.f, 0.f};

  int* so = soffA[wave];
  float4* wp = w4A[wave];

#define LOADX(VB, WB, g)                                                    \
  do {                                                                      \
    _Pragma("unroll") for (int j_ = 0; j_ < 4; ++j_) {                      \
      int sidx_ = (g) * 4 + j_;                                             \
      WB[j_] = wp[sidx_];                                                   \
      VB[j_] = *(const f16x4*)((const char*)xh +                            \
                               (unsigned)(so[sidx_] + lane * 8));           \
    }                                                                       \
  } while (0)

#define FMAX4(VB, WB)                                                       \
  do {                                                                      \
    _Pragma("unroll") for (int j_ = 0; j_ < 4; ++j_)                        \
        _Pragma("unroll") for (int k_ = 0; k_ < 4; ++k_) {                  \
          float xv_ = (float)VB[j_][k_];                                    \
          acc[0][k_] += WB[j_].x * xv_;                                     \
          acc[1][k_] += WB[j_].y * xv_;                                     \
          acc[2][k_] += WB[j_].z * xv_;                                     \
          acc[3][k_] += WB[j_].w * xv_;                                     \
        }                                                                   \
  } while (0)

  for (int base = 0; base < deg; base += 64) {
    int cn = min(64, deg - base);
    int soff = 0;
    float w_l[4] = {0.f, 0.f, 0.f, 0.f};
    if (lane < cn) {
      int s = esrc[e0 + base + lane];
      soff = s * 512;
      float4 sv = ((const float4*)sArr)[s];
      float svv[4] = {sv.x, sv.y, sv.z, sv.w};
#pragma unroll
      for (int h = 0; h < 4; ++h) {
        float e = svv[h] + dloc[h];
        e = (e > 0.f) ? e : 0.2f * e;
        w_l[h] = __expf(e - mn[h]);
      }
    }
#pragma unroll
    for (int h = 0; h < 4; ++h) dsum[h] += w_l[h];
    so[lane] = soff;
    wp[lane] = make_float4(w_l[0], w_l[1], w_l[2], w_l[3]);
    asm volatile("s_waitcnt lgkmcnt(0)" ::: "memory");

    int cng = (cn + 3) >> 2;  // tail slots padded with w=0
    f16x4 vA[4], vB[4];
    float4 wA[4], wB[4];
    LOADX(vA, wA, 0);
    int g = 0;
    while (g + 2 < cng) {
      LOADX(vB, wB, g + 1);
      FMAX4(vA, wA);
      LOADX(vA, wA, g + 2);
      FMAX4(vB, wB);
      g += 2;
    }
    if (g + 1 < cng) {
      LOADX(vB, wB, g + 1);
      FMAX4(vA, wA);
      FMAX4(vB, wB);
    } else {
      FMAX4(vA, wA);
    }
  }
#undef LOADX
#undef FMAX4

  float t0 = dsum[0], t1 = dsum[1], t2 = dsum[2], t3 = dsum[3];
#pragma unroll
  for (int m = 1; m < 64; m <<= 1) {
    t0 += __shfl_xor(t0, m);
    t1 += __shfl_xor(t1, m);
    t2 += __shfl_xor(t2, m);
    t3 += __shfl_xor(t3, m);
  }
  float dnv[4] = {t0 + 1e-16f, t1 + 1e-16f, t2 + 1e-16f, t3 + 1e-16f};
#pragma unroll
  for (int h = 0; h < 4; ++h) {
    f16x4 ov;
#pragma unroll
    for (int k = 0; k < 4; ++k) ov[k] = (f16)(acc[h][k] / dnv[h]);
    *(f16x4*)(outp + (size_t)n * 1024 + h * 256 + lane * 4) = ov;
  }
}

// ---------------------------------------------------------------------------
// HGEMM (fp16 MFMA, fp32 accumulate): C[M,Nn] = A[M,K] @ B[Nn,K]^T
// 128x128 tile, BK=32, 256 thr = 4 waves, wave = 64x64 quadrant (4x4 MFMAs).
// RING-3 LDS pipeline (48 KB, 3 blocks/CU) with depth-2 prefetch + counted
// vmcnt(8); bijective XCD-chunk swizzle for A-panel L2 reuse.
// EPI=0: fused GAT-attention epilogue (s/d scalars, block-reduced gmax).
// EPI=1: bias+ELU epilogue (block-diagonal commuted layer-1 GEMM); per-block
//        A offset = head*hstride with row stride lda.
// ---------------------------------------------------------------------------
template <int EPI>
__global__ __launch_bounds__(256) void k_hgemm_nt(
    const f16* __restrict__ A, const f16* __restrict__ B,
    f16* __restrict__ C, int M, int Nn, int K, int lda, int hstride, int nbx,
    const float* __restrict__ a_src, const float* __restrict__ a_dst,
    const float* __restrict__ bias,
    float* __restrict__ sArr, float* __restrict__ dArr,
    unsigned* __restrict__ gmaxU, int H) {
  __shared__ f16 As[3 * 4096];
  __shared__ f16 Bs[3 * 4096];
  int tid = threadIdx.x;
  int wave = tid >> 6, lane = tid & 63;
  int quad = lane >> 4, l16 = lane & 15;

  // ---- XCD-chunk swizzle (bijective, m204 form) ----
  int nwg = gridDim.x;
  int orig = blockIdx.x;
  int q = nwg >> 3, r = nwg & 7;
  int xcd = orig & 7, pos = orig >> 3;
  int swz = (xcd < r) ? (xcd * (q + 1) + pos)
                      : (r * (q + 1) + (xcd - r) * q + pos);
  int bx = swz % nbx;
  int by = swz / nbx;
  int m0 = by * 128, n0 = bx * 128;
  int wm = (wave & 1) * 64, wn = (wave >> 1) * 64;
  int headOff = (n0 >> 7) * hstride;

  // ---- staging addresses (wave w stages rows w*16.. and 64+w*16.. of A and B)
  int lr = lane >> 2;            // row within 16-row group
  int lc = lane & 3;             // lds chunk slot this lane fills
  int chunk = lc ^ ((lr >> 1) & 3);  // global chunk to fetch (swizzle)
  int rb0 = wave * 16;
  int rb1 = 64 + wave * 16;
  int ga0 = m0 + rb0 + lr; if (ga0 >= M) ga0 = M - 1;
  int ga1 = m0 + rb1 + lr; if (ga1 >= M) ga1 = M - 1;
  const f16* gA0 = A + (size_t)ga0 * lda + headOff + chunk * 8;
  const f16* gA1 = A + (size_t)ga1 * lda + headOff + chunk * 8;
  const f16* gB0 = B + (size_t)(n0 + rb0 + lr) * K + chunk * 8;
  const f16* gB1 = B + (size_t)(n0 + rb1 + lr) * K + chunk * 8;

  // ---- fragment read pointers (chunk = quad ^ ((l16>>1)&3))
  int rsw = (quad ^ ((l16 >> 1) & 3)) * 8;
  const f16* Ard[4];
  const f16* Brd[4];
#pragma unroll
  for (int i = 0; i < 4; ++i) {
    Ard[i] = &As[(wm + i * 16 + l16) * 32 + rsw];
    Brd[i] = &Bs[(wn + i * 16 + l16) * 32 + rsw];
  }

  f32x4 acc[4][4];
#pragma unroll
  for (int i = 0; i < 4; ++i)
#pragma unroll
    for (int j = 0; j < 4; ++j) acc[i][j] = (f32x4)(0.f);

#define GLDS(gp, lp)                                                     \
  __builtin_amdgcn_global_load_lds(                                      \
      (const __attribute__((address_space(1))) void*)(gp),               \
      (__attribute__((address_space(3))) void*)(lp), 16, 0, 0)
#define STAGE(buf, kk)                                                   \
  do {                                                                   \
    GLDS(gA0 + (kk), As + (buf) * 4096 + rb0 * 32);                      \
    GLDS(gA1 + (kk), As + (buf) * 4096 + rb1 * 32);                      \
    GLDS(gB0 + (kk), Bs + (buf) * 4096 + rb0 * 32);                      \
    GLDS(gB1 + (kk), Bs + (buf) * 4096 + rb1 * 32);                      \
  } while (0)
#define COMPUTE(bufidx)                                                       \
  do {                                                                        \
    f16x8 af[4], bf[4];                                                       \
    _Pragma("unroll") for (int i_ = 0; i_ < 4; ++i_)                          \
        af[i_] = *(const f16x8*)(Ard[i_] + (bufidx) * 4096);                  \
    _Pragma("unroll") for (int j_ = 0; j_ < 4; ++j_)                          \
        bf[j_] = *(const f16x8*)(Brd[j_] + (bufidx) * 4096);                  \
    _Pragma("unroll") for (int i_ = 0; i_ < 4; ++i_)                          \
        _Pragma("unroll") for (int j_ = 0; j_ < 4; ++j_)                      \
            acc[i_][j_] = __builtin_amdgcn_mfma_f32_16x16x32_f16(             \
                af[i_], bf[j_], acc[i_][j_], 0, 0, 0);                        \
  } while (0)

  int nt = K >> 5;  // >= 3 always (K = 256 or 512)
  STAGE(0, 0);
  STAGE(1, 32);
  int cur = 0, sb = 2;
  for (int t = 0; t + 2 < nt; ++t) {
    STAGE(sb, (t + 2) << 5);
    asm volatile("s_waitcnt vmcnt(8)\n\ts_barrier" ::: "memory");
    COMPUTE(cur);
    asm volatile("s_barrier" ::: "memory");
    cur = (cur == 2) ? 0 : cur + 1;
    sb = (sb == 2) ? 0 : sb + 1;
  }
  asm volatile("s_waitcnt vmcnt(4)\n\ts_barrier" ::: "memory");
  COMPUTE(cur);
  asm volatile("s_barrier" ::: "memory");
  cur = (cur == 2) ? 0 : cur + 1;
  asm volatile("s_waitcnt vmcnt(0)\n\ts_barrier" ::: "memory");
  COMPUTE(cur);
#undef STAGE
#undef GLDS
#undef COMPUTE

  if (EPI == 1) {
    // ---- bias + ELU store ----
    float bcol[4];
#pragma unroll
    for (int j = 0; j < 4; ++j) bcol[j] = bias[n0 + wn + l16 + j * 16];
#pragma unroll
    for (int i = 0; i < 4; ++i) {
#pragma unroll
      for (int r = 0; r < 4; ++r) {
        int m = m0 + wm + i * 16 + quad * 4 + r;
        if (m < M) {
          f16* Cp = C + (size_t)m * Nn + n0 + wn + l16;
#pragma unroll
          for (int j = 0; j < 4; ++j) {
            float v = acc[i][j][r] + bcol[j];
            v = (v > 0.f) ? v : expm1f(v);
            Cp[j * 16] = (f16)v;
          }
        }
      }
    }
    return;
  }

  // ---- C store ----
#pragma unroll
  for (int i = 0; i < 4; ++i) {
#pragma unroll
    for (int r = 0; r < 4; ++r) {
      int m = m0 + wm + i * 16 + quad * 4 + r;
      if (m < M) {
        f16* Cp = C + (size_t)m * Nn + n0 + wn + l16;
#pragma unroll
        for (int j = 0; j < 4; ++j) Cp[j * 16] = (f16)acc[i][j][r];
      }
    }
  }

  // ---- fused attention scalars ----
  float av[4], ad[4];
#pragma unroll
  for (int j = 0; j < 4; ++j) {
    int col = n0 + wn + l16 + j * 16;
    av[j] = a_src[col];
    ad[j] = a_dst[col];
  }
  float sp[16], dp[16];
#pragma unroll
  for (int i = 0; i < 4; ++i)
#pragma unroll
    for (int r = 0; r < 4; ++r) {
      float ss = 0.f, dd = 0.f;
#pragma unroll
      for (int j = 0; j < 4; ++j) {
        ss += acc[i][j][r] * av[j];
        dd += acc[i][j][r] * ad[j];
      }
#pragma unroll
      for (int msk = 1; msk < 16; msk <<= 1) {
        ss += __shfl_xor(ss, msk);
        dd += __shfl_xor(dd, msk);
      }
      sp[i * 4 + r] = ss;
      dp[i * 4 + r] = dd;
    }

  __syncthreads();  // done reading As/Bs; reuse as float scratch
  float* fb = (float*)As;
  int wv = wn >> 6;
  if (l16 == 0) {
#pragma unroll
    for (int i = 0; i < 4; ++i)
#pragma unroll
      for (int r = 0; r < 4; ++r) {
        int row = wm + i * 16 + quad * 4 + r;
        fb[wv * 128 + row] = sp[i * 4 + r];
        fb[256 + wv * 128 + row] = dp[i * 4 + r];
      }
  }
  __syncthreads();
  float sval = -3.0e38f;
  if (tid < 128) {
    int m = m0 + tid;
    if (m < M) {
      float s = fb[tid] + fb[128 + tid];
      float d = fb[256 + tid] + fb[384 + tid];
      int head = n0 >> 7;
      sArr[(size_t)m * H + head] = s;
      dArr[(size_t)m * H + head] = d;
      sval = s;
    }
  }
  float mx = sval;
#pragma unroll
  for (int msk = 32; msk; msk >>= 1) mx = fmaxf(mx, __shfl_xor(mx, msk));
  __syncthreads();
  if (lane == 0) fb[512 + wave] = mx;
  __syncthreads();
  if (tid == 0) {
    float m01 = fmaxf(fb[512], fb[513]);
    atomicMax(&gmaxU[n0 >> 7], ordf(m01));
  }
}

// ---------------------------------------------------------------------------
// Segment softmax + aggregation (layers 2,3): ONE WAVE PER NODE, no barriers.
// esrc holds resolved src ids; per-chunk (soff, w) pairs staged head-major
// in LDS, stride 66 (conflict-free). Inner loop: 1 ds_read_b64 per edge +
// pipelined 16B gathers, groups of edges, double-buffered registers.
// HH==1 (layer 3, 128-dim rows): TWO edges per slot (lanes 0-31 / 32-63).
// Shift = leaky(gmax + d_n) >= segment max (leaky monotone; softmax
// shift-invariant). gmax passed as order-preserving uint.
// ---------------------------------------------------------------------------
template <int HH, int CT, bool DOELU, typename OutT>
__global__ __launch_bounds__(256) void k_aggregate(
    const f16* __restrict__ hin, const float* __restrict__ sArr,
    const float* __restrict__ dArr, const int* __restrict__ row_ptr,
    const int* __restrict__ esrc, const unsigned* __restrict__ gmaxU,
    const float* __restrict__ bias, OutT* __restrict__ outp, int N, int E) {
  constexpr int VEC = (HH == 1) ? 4 : (CT / 64);
  constexpr int CPER = CT / HH;
  using gvec = typename VecT<VEC>::T;

  __shared__ int2 pairs[4][HH * 66];  // [wave][h*66 + edge] = {soff, w_h}

  int wave = threadIdx.x >> 6;
  int lane = threadIdx.x & 63;
  int n = blockIdx.x * 4 + wave;
  if (n >= N) return;
  int e0 = row_ptr[n];
  int deg = row_ptr[n + 1] - e0;

  const int myhead = (HH == 1) ? 0 : (lane * VEC) / CPER;
  const int l32 = lane & 31, half = lane >> 5;
  const int laneByte = (HH == 1) ? l32 * 8 : lane * VEC * 2;

  float dloc[HH], mn[HH];
#pragma unroll
  for (int h = 0; h < HH; ++h) {
    dloc[h] = dArr[n * HH + h];
    float m = unordf(gmaxU[h]) + dloc[h];
    mn[h] = (m > 0.f) ? m : 0.2f * m;
  }

  float acc[VEC];
#pragma unroll
  for (int k = 0; k < VEC; ++k) acc[k] = 0.f;
  float dsum[HH];
#pragma unroll
  for (int h = 0; h < HH; ++h) dsum[h] = 0.f;

  int2* pw = &pairs[wave][0];
  const int2* pr = &pairs[wave][myhead * 66];

#define PIDX(g, j) ((HH == 1) ? ((g) * 8 + (j) * 2 + half) : ((g) * 4 + (j)))
#define LOADG(VB, WB, g)                                                      \
  do {                                                                        \
    _Pragma("unroll") for (int j_ = 0; j_ < 4; ++j_) {                        \
      int2 p_ = pr[PIDX(g, j_)];                                              \
      WB[j_] = __int_as_float(p_.y);                                          \
      VB[j_] = *(const gvec*)((const char*)hin + (unsigned)(p_.x + laneByte));\
    }                                                                         \
  } while (0)

#define FMAG(VB, WB)                                                          \
  do {                                                                        \
    _Pragma("unroll") for (int j_ = 0; j_ < 4; ++j_)                          \
        _Pragma("unroll") for (int k_ = 0; k_ < VEC; ++k_)                    \
            acc[k_] += WB[j_] * (float)VB[j_][k_];                            \
  } while (0)

  for (int base = 0; base < deg; base += 64) {
    int cn = min(64, deg - base);

    int soff = 0;
    float w_l[HH];
#pragma unroll
    for (int h = 0; h < HH; ++h) w_l[h] = 0.f;
    if (lane < cn) {
      int s = esrc[e0 + base + lane];
      soff = s * (CT * 2);
      if (HH == 4) {
        float4 sv = ((const float4*)sArr)[s];
        float svv[4] = {sv.x, sv.y, sv.z, sv.w};
#pragma unroll
        for (int h = 0; h < 4; ++h) {
          float e = svv[h] + dloc[h];
          e = (e > 0.f) ? e : 0.2f * e;
          w_l[h] = __expf(e - mn[h]);
        }
      } else {
        float e = sArr[s] + dloc[0];
        e = (e > 0.f) ? e : 0.2f * e;
        w_l[0] = __expf(e - mn[0]);
      }
    }
#pragma unroll
    for (int h = 0; h < HH; ++h) dsum[h] += w_l[h];

#pragma unroll
    for (int h = 0; h < HH; ++h)
      pw[h * 66 + lane] = make_int2(soff, __float_as_int(w_l[h]));
    asm volatile("s_waitcnt lgkmcnt(0)" ::: "memory");

    int cng = (HH == 1) ? ((cn + 7) >> 3) : ((cn + 3) >> 2);
    gvec vA[4], vB[4];
    float wA[4], wB[4];
    LOADG(vA, wA, 0);
    int g = 0;
    while (g + 2 < cng) {
      LOADG(vB, wB, g + 1);
      FMAG(vA, wA);
      LOADG(vA, wA, g + 2);
      FMAG(vB, wB);
      g += 2;
    }
    if (g + 1 < cng) {
      LOADG(vB, wB, g + 1);
      FMAG(vA, wA);
      FMAG(vB, wB);
    } else {
      FMAG(vA, wA);
    }
  }
#undef LOADG
#undef FMAG
#undef PIDX

  if (HH == 1) {
#pragma unroll
    for (int k = 0; k < VEC; ++k) acc[k] += __shfl_xor(acc[k], 32);
  }

  float dn;
  if (HH == 4) {
    float t0 = dsum[0], t1 = dsum[1], t2 = dsum[2], t3 = dsum[3];
#pragma unroll
    for (int m = 1; m < 64; m <<= 1) {
      t0 += __shfl_xor(t0, m);
      t1 += __shfl_xor(t1, m);
      t2 += __shfl_xor(t2, m);
      t3 += __shfl_xor(t3, m);
    }
    dn = (myhead < 2) ? (myhead == 0 ? t0 : t1) : (myhead == 2 ? t2 : t3);
  } else {
    float t0 = dsum[0];
#pragma unroll
    for (int m = 1; m < 64; m <<= 1) t0 += __shfl_xor(t0, m);
    dn = t0;
  }
  dn += 1e-16f;

  if (HH == 1) {
    if (lane < 32) {
      struct alignas(16) OutV { OutT v[4]; } ov;
#pragma unroll
      for (int k = 0; k < 4; ++k) {
        float v = acc[k] / dn + bias[l32 * 4 + k];
        if (DOELU) v = (v > 0.f) ? v : expm1f(v);
        ov.v[k] = (OutT)v;
      }
      *(OutV*)(outp + (size_t)n * CT + l32 * 4) = ov;
    }
  } else {
    struct alignas(sizeof(OutT) * VEC) OutV { OutT v[VEC]; } ov;
#pragma unroll
    for (int k = 0; k < VEC; ++k) {
      float v = acc[k] / dn + bias[lane * VEC + k];
      if (DOELU) v = (v > 0.f) ? v : expm1f(v);
      ov.v[k] = (OutT)v;
    }
    *(OutV*)(outp + (size_t)n * CT + lane * VEC) = ov;
  }
}

// ---------------------------------------------------------------------------
// Allocation head (Wh1 staged in LDS, persistent blocks)
// ---------------------------------------------------------------------------
__global__ __launch_bounds__(256) void k_head(
    const float* __restrict__ emb, const float* __restrict__ Wh1,
    const float* __restrict__ bh1, const float* __restrict__ Wh2,
    const float* __restrict__ bh2, float* __restrict__ scores, int N) {
  __shared__ float w1s[64 * 132];
  __shared__ float w2s[64];
  __shared__ float b1s[64];
  int t = threadIdx.x;
  for (int i = t; i < 64 * 32; i += 256) {
    int r = i >> 5, c4 = i & 31;
    float4 v = ((const float4*)Wh1)[i];
    *(float4*)&w1s[r * 132 + c4 * 4] = v;
  }
  if (t < 64) { w2s[t] = Wh2[t]; b1s[t] = bh1[t]; }
  __syncthreads();
  float b2v = bh2[0];
  int wave = t >> 6, lane = t & 63;
  int gw = blockIdx.x * 4 + wave;
  int nw = gridDim.x * 4;
  for (int n = gw; n < N; n += nw) {
    float2 xv = ((const float2*)(emb + (size_t)n * 128))[lane];
    float z = b1s[lane];
#pragma unroll
    for (int j = 0; j < 32; ++j) {
      float4 w = *(const float4*)&w1s[lane * 132 + 4 * j];
      float a0 = __shfl(xv.x, 2 * j);
      float a1 = __shfl(xv.y, 2 * j);
      float a2 = __shfl(xv.x, 2 * j + 1);
      float a3 = __shfl(xv.y, 2 * j + 1);
      z += w.x * a0 + w.y * a1 + w.z * a2 + w.w * a3;
    }
    z = fmaxf(z, 0.f);
    float v = z * w2s[lane];
#pragma unroll
    for (int off = 32; off; off >>= 1) v += __shfl_down(v, off);
    if (lane == 0) scores[n] = 1.f / (1.f + __expf(-(v + b2v)));
  }
}

// ---------------------------------------------------------------------------

extern "C" void kernel_launch(void* const* d_in, const int* in_sizes, int n_in,
                              void* d_out, int out_size, void* d_ws, size_t ws_size,
                              hipStream_t stream) {
  const float* x   = (const float*)d_in[0];
  const int*   ei  = (const int*)d_in[1];
  const float* W1  = (const float*)d_in[2];
  const float* as1 = (const float*)d_in[3];
  const float* ad1 = (const float*)d_in[4];
  const float* b1  = (const float*)d_in[5];
  const float* W2  = (const float*)d_in[6];
  const float* as2 = (const float*)d_in[7];
  const float* ad2 = (const float*)d_in[8];
  const float* b2  = (const float*)d_in[9];
  const float* W3  = (const float*)d_in[10];
  const float* as3 = (const float*)d_in[11];
  const float* ad3 = (const float*)d_in[12];
  const float* b3  = (const float*)d_in[13];
  const float* Wh1 = (const float*)d_in[14];
  const float* bh1 = (const float*)d_in[15];
  const float* Wh2 = (const float*)d_in[16];
  const float* bh2 = (const float*)d_in[17];
  float* out = (float*)d_out;

  const int F = 256, HC = 512, H = 4, C = 128;
  const int N = in_sizes[0] / F;
  const int E = in_sizes[1] / 2;
  const int Et = E + N;
  const int* srcArr = ei;
  const int* dstArr = ei + E;

  char* ws = (char*)d_ws;
  size_t off = 0;
  auto alloc = [&](size_t bytes) -> void* {
    void* p = ws + off;
    off += (bytes + 255) & ~(size_t)255;
    return p;
  };
  // xagg4 [N,4,256] f16; h16 [N,512] f16 aliases its first half (xagg4 is
  // dead by the time layer-2's GEMM writes h16).
  f16*   xagg4  = (f16*)alloc((size_t)N * 1024 * 2);
  f16*   h16    = xagg4;
  f16*   hAgg   = (f16*)alloc((size_t)N * HC * 2);
  f16*   xh     = (f16*)alloc((size_t)N * F * 2);
  f16*   W1h    = (f16*)alloc((size_t)HC * F * 2);
  f16*   W2h    = (f16*)alloc((size_t)HC * HC * 2);
  f16*   W3h    = (f16*)alloc((size_t)C * HC * 2);
  float* wsb    = (float*)alloc((size_t)8 * 256 * 4);
  int* row_ptr  = (int*)alloc((size_t)(N + 1) * 4);
  // zero region: cnt (N ints) + 3x4 gmax uints, one memset
  char* zr      = (char*)alloc((size_t)N * 4 + 64);
  int* cnt      = (int*)zr;
  unsigned* gm1 = (unsigned*)(zr + (size_t)N * 4);
  unsigned* gm2 = gm1 + 4;
  unsigned* gm3 = gm1 + 8;
  int* cursor   = (int*)alloc((size_t)N * 4);
  int* esrc     = (int*)alloc((size_t)Et * 4);
  float* sArr   = (float*)alloc((size_t)N * H * 4);
  float* dArr   = (float*)alloc((size_t)N * H * 4);
  int* bsum     = (int*)alloc((size_t)1028 * 4);
  (void)ws_size; (void)n_in; (void)out_size;

  // ---- CSR build ----
  hipMemsetAsync(zr, 0, (size_t)N * 4 + 64, stream);
  int eb = (Et + 255) / 256;
  int nb = (N + 1023) / 1024;
  k_count<<<eb, 256, 0, stream>>>(dstArr, cnt, E, Et);
  k_scanA<<<nb, 256, 0, stream>>>(cnt, row_ptr, bsum, N);
  k_scanB<<<1, 1024, 0, stream>>>(bsum, nb);
  k_scanC<<<(N + 256) / 256, 256, 0, stream>>>(row_ptr, cursor, bsum, N, nb);
  k_fill<<<eb, 256, 0, stream>>>(dstArr, srcArr, cursor, esrc, E, Et);

  // ---- fp16 conversions (one launch) ----
  int c0 = N * F / 4, c1 = HC * F / 4, c2 = HC * HC / 4, c3 = C * HC / 4;
  int ctot = c0 + c1 + c2 + c3;
  k_f2h4<<<(ctot + 255) / 256, 256, 0, stream>>>(x, xh, c0, W1, W1h, c1,
                                                 W2, W2h, c2, W3, W3h, c3);

  int aggGrid = (N + 3) / 4;
  int mblk = (N + 127) / 128;
  int nblk1 = 4 * mblk;   // layers 1,2: nbx=4
  int nblk3 = mblk;       // layer 3:    nbx=1

  // ---- layer 1 (commuted): s/d GEMV -> x-aggregate -> block-diag GEMM ----
  k_ws<<<8, 256, 0, stream>>>(W1, as1, ad1, wsb);
  k_sd<<<1024, 256, 0, stream>>>(xh, wsb, sArr, dArr, gm1, N);
  k_aggx<<<aggGrid, 256, 0, stream>>>(xh, sArr, dArr, row_ptr, esrc, gm1,
                                      xagg4, N, E);
  k_hgemm_nt<1><<<nblk1, 256, 0, stream>>>(
      xagg4, W1h, hAgg, N, HC, F, 1024, 256, 4,
      nullptr, nullptr, b1, nullptr, nullptr, nullptr, H);

  // ---- layer 2: H*C -> H*C, elu ----
  k_hgemm_nt<0><<<nblk1, 256, 0, stream>>>(
      hAgg, W2h, h16, N, HC, HC, HC, 0, 4,
      as2, ad2, nullptr, sArr, dArr, gm2, H);
  k_aggregate<4, 512, true, f16><<<aggGrid, 256, 0, stream>>>(
      h16, sArr, dArr, row_ptr, esrc, gm2, b2, hAgg, N, E);

  // ---- layer 3: H*C -> C, single head, no concat/elu -> embeddings ----
  k_hgemm_nt<0><<<nblk3, 256, 0, stream>>>(
      hAgg, W3h, h16, N, C, HC, HC, 0, 1,
      as3, ad3, nullptr, sArr, dArr, gm3, 1);
  k_aggregate<1, 128, false, float><<<aggGrid, 256, 0, stream>>>(
      h16, sArr, dArr, row_ptr, esrc, gm3, b3, out, N, E);

  // ---- allocation head ----
  k_head<<<512, 256, 0, stream>>>(out, Wh1, bh1, Wh2, bh2, out + (size_t)N * C, N);
}